// Round 14
// baseline (203.535 us; speedup 1.0000x reference)
//
#include <hip/hip_runtime.h>
#include <cstdint>

// Autoformer encoder block, B=8 S=1024 D=512 H=8 dp=64, K=25 moving avg.
// Math simplifications (exact):
//  - depth-axis FFT autocorr == 64-lag linear correlation; softmax has 960
//    zero logits -> collapsed weighted sum over 64 lags + Vsum rank-1 term.
//  - trend2 cancels; seasonal_init + trend_init == x.
// R14: FFN1 moved to a 256x256-tile kernel (1.5x fewer staged bytes/FLOP,
// exact one-fill grid); rest = R13.

typedef float f32x4 __attribute__((ext_vector_type(4)));
typedef __bf16 bf16x8 __attribute__((ext_vector_type(8)));
typedef _Float16 h2t __attribute__((ext_vector_type(2)));
typedef unsigned short u16;
typedef unsigned int u32;
typedef u32 u32x4 __attribute__((ext_vector_type(4)));

__device__ __forceinline__ u16 f2bf(float f) {
  unsigned int u = __float_as_uint(f);
  u = (u + 0x7FFFu + ((u >> 16) & 1u)) >> 16;
  return (u16)u;
}

__device__ __forceinline__ float bf2f(u16 b) { return __uint_as_float((u32)b << 16); }

__device__ __forceinline__ u16 f2h(float f) {
  _Float16 hv = (_Float16)f;
  u16 b;
  __builtin_memcpy(&b, &hv, 2);
  return b;
}

__device__ __forceinline__ float dot2h(u32 qp, u32 kp_, float c) {
#if __has_builtin(__builtin_amdgcn_fdot2)
  return __builtin_amdgcn_fdot2(__builtin_bit_cast(h2t, qp),
                                __builtin_bit_cast(h2t, kp_), c, false);
#else
  h2t q = __builtin_bit_cast(h2t, qp), k = __builtin_bit_cast(h2t, kp_);
  c = fmaf((float)q.x, (float)k.x, c);
  return fmaf((float)q.y, (float)k.y, c);
#endif
}

__device__ __forceinline__ void gload_lds16(const void* g, void* l) {
  __builtin_amdgcn_global_load_lds((__attribute__((address_space(1))) void*)g,
                                   (__attribute__((address_space(3))) void*)l,
                                   16, 0, 0);
}

// ======= merged prep: weight transposes + bias concat + moving average =====
__global__ __launch_bounds__(256) void prep_kernel(
    const float* __restrict__ wq, const float* __restrict__ wk,
    const float* __restrict__ wv, const float* __restrict__ wo,
    const float* __restrict__ w1, const float* __restrict__ w2,
    const float* __restrict__ bq, const float* __restrict__ bk,
    u16* __restrict__ wqkt, u16* __restrict__ wvt, u16* __restrict__ wot,
    u16* __restrict__ w1t, u16* __restrict__ w2t, float* __restrict__ qkbias,
    const float* __restrict__ x, u16* __restrict__ seas_bf,
    u16* __restrict__ a64, float* __restrict__ srow) {
  __shared__ float tile[32][33];
  int i = blockIdx.x;
  int tid = threadIdx.x;
  int tx = tid & 31, ty = tid >> 5;
  if (i >= 3076) {
    // ---- moving average path ----
    int blk = i - 3076;
    int sc = blk & 127, b = blk >> 7;
    int d = tid * 2;
    const float* xb = x + (size_t)b * 1024 * 512 + d;
    int s0 = sc * 8;
    int lo = max(s0 - 12, 0), hi = min(s0 + 12, 1023);
    float sx = 0.f, sy = 0.f;
    for (int j = lo; j <= hi; ++j) {
      float2 v = *(const float2*)&xb[(size_t)j * 512];
      sx += v.x;
      sy += v.y;
    }
    float ax = 0.f, ay = 0.f;
#pragma unroll
    for (int s = s0; s < s0 + 8; ++s) {
      int l2 = max(s - 12, 0), h2 = min(s + 12, 1023);
      float invc = 1.f / (float)(h2 - l2 + 1);
      float2 xv = *(const float2*)&xb[(size_t)s * 512];
      float sex = xv.x - sx * invc;
      float sey = xv.y - sy * invc;
      size_t idx = (size_t)(b * 1024 + s) * 512 + d;
      u32 pk = (u32)f2bf(sex) | ((u32)f2bf(sey) << 16);
      *(u32*)&seas_bf[idx] = pk;
      if (s < 64) *(u32*)&a64[(size_t)(b * 64 + s) * 512 + d] = pk;
      ax += sex;
      ay += sey;
      if (s - 12 >= 0) {
        float2 v = *(const float2*)&xb[(size_t)(s - 12) * 512];
        sx -= v.x;
        sy -= v.y;
      }
      if (s + 13 <= 1023) {
        float2 v = *(const float2*)&xb[(size_t)(s + 13) * 512];
        sx += v.x;
        sy += v.y;
      }
    }
    atomicAdd(&srow[b * 512 + d], ax);
    atomicAdd(&srow[b * 512 + d + 1], ay);
    return;
  }
  if (i >= 3072) {
    int idx = (i - 3072) * 256 + tid;
    qkbias[idx] = idx < 512 ? bq[idx] : bk[idx - 512];
    return;
  }
  const float* src;
  u16* dst;
  int R, C, bx, by;
  if (i < 1024) {
    int w = i >> 8, l = i & 255;
    src = (w == 0 ? wq : w == 1 ? wk : w == 2 ? wv : wo);
    dst = (w == 0 ? wqkt : w == 1 ? wqkt + 512 * 512 : w == 2 ? wvt : wot);
    R = 512; C = 512; bx = l & 15; by = l >> 4;
  } else if (i < 2048) {
    int l = i - 1024;
    src = w1; dst = w1t; R = 512; C = 2048; bx = l & 15; by = l >> 4;
  } else {
    int l = i - 2048;
    src = w2; dst = w2t; R = 2048; C = 512; bx = l & 63; by = l >> 6;
  }
  int r0 = bx * 32, c0 = by * 32;
#pragma unroll
  for (int k = 0; k < 4; ++k)
    tile[ty + 8 * k][tx] = src[(size_t)(r0 + ty + 8 * k) * C + c0 + tx];
  __syncthreads();
#pragma unroll
  for (int k = 0; k < 4; ++k)
    dst[(size_t)(c0 + ty + 8 * k) * R + r0 + tx] = f2bf(tile[tx][ty + 8 * k]);
}

// ---------------- Vsum[b,n] = srow[b,:] @ wv[:,n] + 1024*bv[n] --------------
__global__ __launch_bounds__(256) void vsum_kernel(
    const float* __restrict__ srow, const float* __restrict__ wv,
    const float* __restrict__ bv, float* __restrict__ vsum) {
  int blk = blockIdx.x;  // 16
  int b = blk >> 1;
  int n = (blk & 1) * 256 + threadIdx.x;
  float a0 = 0.f, a1 = 0.f, a2 = 0.f, a3 = 0.f;
  float a4 = 0.f, a5 = 0.f, a6 = 0.f, a7 = 0.f;
  const float* sr = srow + b * 512;
  for (int k = 0; k < 512; k += 8) {
    a0 = fmaf(sr[k + 0], wv[(size_t)(k + 0) * 512 + n], a0);
    a1 = fmaf(sr[k + 1], wv[(size_t)(k + 1) * 512 + n], a1);
    a2 = fmaf(sr[k + 2], wv[(size_t)(k + 2) * 512 + n], a2);
    a3 = fmaf(sr[k + 3], wv[(size_t)(k + 3) * 512 + n], a3);
    a4 = fmaf(sr[k + 4], wv[(size_t)(k + 4) * 512 + n], a4);
    a5 = fmaf(sr[k + 5], wv[(size_t)(k + 5) * 512 + n], a5);
    a6 = fmaf(sr[k + 6], wv[(size_t)(k + 6) * 512 + n], a6);
    a7 = fmaf(sr[k + 7], wv[(size_t)(k + 7) * 512 + n], a7);
  }
  vsum[b * 512 + n] = ((a0 + a1) + (a2 + a3)) + ((a4 + a5) + (a6 + a7)) + 1024.f * bv[n];
}

// ============ 8-phase-family GEMM: 256x128 tile, BK=64, 8 waves =============
// OMODE: 1=bf16, 2=f16. KSPLIT: z>0 -> partial to Cv2 (bias only z==0).
template <int RELU, int OMODE, int KSPLIT>
__global__ __launch_bounds__(512, 1) void gemm8p_kernel(
    const u16* __restrict__ A, const u16* __restrict__ Bt,
    const float* __restrict__ bias, void* __restrict__ Cv, void* __restrict__ Cv2,
    int M, int N, int K) {
  __shared__ u16 As[3][2][256 * 32];
  __shared__ u16 Bs[3][2][128 * 32];
  const int tid = threadIdx.x;
  const int wid = tid >> 6, lane = tid & 63;
  const int wm = wid >> 2, wn = wid & 3;
  const int la = lane & 15, lg = lane >> 4;
  int nwg = gridDim.x * gridDim.y;
  int lin = blockIdx.y * gridDim.x + blockIdx.x;
  int swz = (lin & 7) * (nwg >> 3) + (lin >> 3);
  int bx = swz / gridDim.y, by = swz % gridDim.y;
  const int row0 = bx * 256, col0 = by * 128;
  const int z = (KSPLIT > 1) ? (int)blockIdx.z : 0;
  const int kbeg = z * (K / KSPLIT);
  const int nt = (K / KSPLIT) / 64;
  f32x4 acc[8][2] = {};

  auto stageh = [&](int buf, int h, int k0) {
    int kh = k0 + h * 32;
    {
      int p = tid, r = p >> 2, cg = (p & 3) ^ ((r >> 1) & 3);
      gload_lds16(A + (size_t)(row0 + r) * K + kh + cg * 8,
                  ((char*)&As[buf][h][0]) + p * 16);
    }
    {
      int p = tid + 512, r = p >> 2, cg = (p & 3) ^ ((r >> 1) & 3);
      gload_lds16(A + (size_t)(row0 + r) * K + kh + cg * 8,
                  ((char*)&As[buf][h][0]) + p * 16);
    }
    {
      int p = tid, r = p >> 2, cg = (p & 3) ^ ((r >> 1) & 3);
      gload_lds16(Bt + (size_t)(col0 + r) * K + kh + cg * 8,
                  ((char*)&Bs[buf][h][0]) + p * 16);
    }
  };

  stageh(0, 0, kbeg);
  stageh(0, 1, kbeg);
  stageh(1, 0, kbeg + 64);
  stageh(1, 1, kbeg + 64);
  asm volatile("s_waitcnt vmcnt(6)" ::: "memory");
  __builtin_amdgcn_s_barrier();
  __builtin_amdgcn_sched_barrier(0);

  for (int t = 0; t < nt; ++t) {
    const int buf = t % 3;
    const int nbuf = (t + 2) % 3;
    const bool pre = (t + 2 < nt);
#pragma unroll
    for (int h = 0; h < 2; ++h) {
      bf16x8 af[8], bf[2];
#pragma unroll
      for (int mf = 0; mf < 8; ++mf) {
        int r = wm * 128 + mf * 16 + la;
        int cp = lg ^ ((r >> 1) & 3);
        af[mf] = *(const bf16x8*)&As[buf][h][r * 32 + cp * 8];
      }
#pragma unroll
      for (int nf = 0; nf < 2; ++nf) {
        int r = wn * 32 + nf * 16 + la;
        int cp = lg ^ ((r >> 1) & 3);
        bf[nf] = *(const bf16x8*)&Bs[buf][h][r * 32 + cp * 8];
      }
      if (pre) stageh(nbuf, h, kbeg + (t + 2) * 64);
      __builtin_amdgcn_sched_barrier(0);
      __builtin_amdgcn_s_barrier();
      __builtin_amdgcn_s_setprio(1);
#pragma unroll
      for (int mf = 0; mf < 8; ++mf)
#pragma unroll
        for (int nf = 0; nf < 2; ++nf)
          acc[mf][nf] = __builtin_amdgcn_mfma_f32_16x16x32_bf16(af[mf], bf[nf], acc[mf][nf], 0, 0, 0);
      __builtin_amdgcn_s_setprio(0);
      __builtin_amdgcn_sched_barrier(0);
      if (h == 0) __builtin_amdgcn_s_barrier();
    }
    if (pre)
      asm volatile("s_waitcnt vmcnt(6)" ::: "memory");
    else if (t + 1 < nt)
      asm volatile("s_waitcnt vmcnt(0)" ::: "memory");
    __builtin_amdgcn_s_barrier();
    __builtin_amdgcn_sched_barrier(0);
  }

  void* Cout = (z == 0) ? Cv : Cv2;
#pragma unroll
  for (int mf = 0; mf < 8; ++mf) {
    int r = row0 + wm * 128 + mf * 16 + lg * 4;
#pragma unroll
    for (int nf = 0; nf < 2; ++nf) {
      int cc = col0 + wn * 32 + nf * 16 + la;
      float bvv = (z == 0) ? bias[cc] : 0.f;
#pragma unroll
      for (int j = 0; j < 4; ++j) {
        float v = acc[mf][nf][j] + bvv;
        if (RELU) v = fmaxf(v, 0.f);
        if constexpr (OMODE == 1)
          ((u16*)Cout)[(size_t)(r + j) * N + cc] = f2bf(v);
        else
          ((u16*)Cout)[(size_t)(r + j) * N + cc] = f2h(v);
      }
    }
  }
}

// ============ 256x256-tile GEMM: BK=32, triple-buffer, counted vmcnt ========
// 512 threads, 8 waves (2M x 4N), per-wave 128x64 out (8x4 frags, 32 MFMA per
// K-tile). LDS 96 KB. Same 0-conflict swizzle + R8 counted-vmcnt discipline.
template <int RELU>
__global__ __launch_bounds__(512, 1) void gemm256_kernel(
    const u16* __restrict__ A, const u16* __restrict__ Bt,
    const float* __restrict__ bias, u16* __restrict__ C, int M, int N, int K) {
  constexpr int BK = 32;
  __shared__ u16 As[3][256 * BK];  // 16 KB each
  __shared__ u16 Bs[3][256 * BK];  // 16 KB each
  const int tid = threadIdx.x;
  const int wid = tid >> 6, lane = tid & 63;
  const int wm = wid >> 2, wn = wid & 3;
  const int la = lane & 15, lg = lane >> 4;
  int nwg = gridDim.x * gridDim.y;
  int lin = blockIdx.y * gridDim.x + blockIdx.x;
  int swz = (lin & 7) * (nwg >> 3) + (lin >> 3);
  int bx = swz / gridDim.y, by = swz % gridDim.y;
  const int row0 = bx * 256, col0 = by * 256;
  const int nt = K / BK;
  f32x4 acc[8][4] = {};

  // 256 rows x 4 chunks = 1024 chunks per matrix; thread stages p=tid, tid+512
  auto stage = [&](int buf, int k0) {
#pragma unroll
    for (int j = 0; j < 2; ++j) {
      int p = tid + j * 512;
      int r = p >> 2, cg = (p & 3) ^ ((r >> 1) & 3);
      gload_lds16(A + (size_t)(row0 + r) * K + k0 + cg * 8, ((char*)As[buf]) + p * 16);
      gload_lds16(Bt + (size_t)(col0 + r) * K + k0 + cg * 8, ((char*)Bs[buf]) + p * 16);
    }
  };

  stage(0, 0);
  stage(1, BK);
  asm volatile("s_waitcnt vmcnt(4)" ::: "memory");  // stage(0) landed
  __builtin_amdgcn_s_barrier();
  __builtin_amdgcn_sched_barrier(0);

  for (int t = 0; t < nt; ++t) {
    const int cur = t % 3;
    if (t + 2 < nt) stage((t + 2) % 3, (t + 2) * BK);
    __builtin_amdgcn_sched_barrier(0);
    bf16x8 af[8], bfr[4];
#pragma unroll
    for (int mf = 0; mf < 8; ++mf) {
      int r = wm * 128 + mf * 16 + la;
      int cp = lg ^ ((r >> 1) & 3);
      af[mf] = *(const bf16x8*)(((const char*)As[cur]) + r * 64 + cp * 16);
    }
#pragma unroll
    for (int nf = 0; nf < 4; ++nf) {
      int r = wn * 64 + nf * 16 + la;
      int cp = lg ^ ((r >> 1) & 3);
      bfr[nf] = *(const bf16x8*)(((const char*)Bs[cur]) + r * 64 + cp * 16);
    }
    __builtin_amdgcn_s_setprio(1);
#pragma unroll
    for (int mf = 0; mf < 8; ++mf)
#pragma unroll
      for (int nf = 0; nf < 4; ++nf)
        acc[mf][nf] = __builtin_amdgcn_mfma_f32_16x16x32_bf16(af[mf], bfr[nf], acc[mf][nf], 0, 0, 0);
    __builtin_amdgcn_s_setprio(0);
    if (t + 2 < nt)
      asm volatile("s_waitcnt vmcnt(4)" ::: "memory");  // stage(t+1) landed
    else
      asm volatile("s_waitcnt vmcnt(0)" ::: "memory");
    __builtin_amdgcn_s_barrier();
    __builtin_amdgcn_sched_barrier(0);
  }

#pragma unroll
  for (int mf = 0; mf < 8; ++mf) {
    int r = row0 + wm * 128 + mf * 16 + lg * 4;
#pragma unroll
    for (int nf = 0; nf < 4; ++nf) {
      int cc = col0 + wn * 64 + nf * 16 + la;
      float bvv = bias[cc];
#pragma unroll
      for (int j = 0; j < 4; ++j) {
        float v = acc[mf][nf][j] + bvv;
        if (RELU) v = fmaxf(v, 0.f);
        C[(size_t)(r + j) * N + cc] = f2bf(v);
      }
    }
  }
}

// ---------------- small GEMM for V projection (transposed bf16 scatter) -----
__global__ __launch_bounds__(256, 6) void gemm_v_kernel(
    const u16* __restrict__ A, const u16* __restrict__ Bt,
    const float* __restrict__ bias, u16* __restrict__ Cv, int M, int N, int K) {
  constexpr int BK = 32;
  __shared__ u16 As[2][128 * BK];
  __shared__ u16 Bs[2][64 * BK];
  const int tid = threadIdx.x;
  const int wid = tid >> 6, lane = tid & 63;
  const int wm = wid >> 1, wn = wid & 1;
  const int la = lane & 15, lg = lane >> 4;
  const int row0 = blockIdx.x * 128, col0 = blockIdx.y * 64;
  const int ksteps = K / BK;
  f32x4 acc[4][2] = {};

  auto stage = [&](int buf, int k0) {
    {
      int p = tid, r = p >> 2, cg = (p & 3) ^ ((r >> 1) & 3);
      gload_lds16(A + (size_t)(row0 + r) * K + k0 + cg * 8, ((char*)As[buf]) + p * 16);
    }
    {
      int p = tid + 256, r = p >> 2, cg = (p & 3) ^ ((r >> 1) & 3);
      gload_lds16(A + (size_t)(row0 + r) * K + k0 + cg * 8, ((char*)As[buf]) + p * 16);
    }
    {
      int p = tid, r = p >> 2, cg = (p & 3) ^ ((r >> 1) & 3);
      gload_lds16(Bt + (size_t)(col0 + r) * K + k0 + cg * 8, ((char*)Bs[buf]) + p * 16);
    }
  };

  stage(0, 0);
  __syncthreads();
  for (int t = 0; t < ksteps; ++t) {
    const int cur = t & 1;
    if (t + 1 < ksteps) stage(cur ^ 1, (t + 1) * BK);
    bf16x8 af[4], bfr[2];
#pragma unroll
    for (int m = 0; m < 4; ++m) {
      int r = wm * 64 + m * 16 + la;
      int cp = lg ^ ((r >> 1) & 3);
      af[m] = *(const bf16x8*)(((const char*)As[cur]) + r * 64 + cp * 16);
    }
#pragma unroll
    for (int n = 0; n < 2; ++n) {
      int r = wn * 32 + n * 16 + la;
      int cp = lg ^ ((r >> 1) & 3);
      bfr[n] = *(const bf16x8*)(((const char*)Bs[cur]) + r * 64 + cp * 16);
    }
#pragma unroll
    for (int m = 0; m < 4; ++m)
#pragma unroll
      for (int n = 0; n < 2; ++n)
        acc[m][n] = __builtin_amdgcn_mfma_f32_16x16x32_bf16(af[m], bfr[n], acc[m][n], 0, 0, 0);
    __syncthreads();
  }

#pragma unroll
  for (int m = 0; m < 4; ++m) {
    int r = row0 + wm * 64 + m * 16 + lg * 4;
#pragma unroll
    for (int n = 0; n < 2; ++n) {
      int cc = col0 + wn * 32 + n * 16 + la;
      float bvv = bias[cc];
#pragma unroll
      for (int j = 0; j < 4; ++j) {
        float v = acc[m][n][j] + bvv;
        int rr = r + j;
        int bb = rr >> 6, tt = rr & 63, hh = cc >> 6, dd = cc & 63;
        Cv[(((size_t)bb * 8 + hh) * 64 + dd) * 64 + tt] = f2bf(v);
      }
    }
  }
}

// ---------- attention: 64-lag autocorr (f16 dot2) + MFMA PV, 16-row chunks --
__global__ __launch_bounds__(256) void attn_mfma_kernel(
    const u16* __restrict__ qk, const u16* __restrict__ v64t,
    const float* __restrict__ vsum, u16* __restrict__ attn_bf) {
  __shared__ u32 qE[16][64];
  __shared__ u32 qO[16][64];
  __shared__ u32 kp[16][32];
  __shared__ u16 coef[16][64];
  __shared__ u16 vtt[64][64];
  __shared__ float zc[16];
  __shared__ float Vs[64];
  int bid = blockIdx.x;
  int scnk = bid & 63, h = (bid >> 6) & 7, b = bid >> 9;
  int tid = threadIdx.x, wid = tid >> 6, lane = tid & 63;
  int bh = b * 8 + h;
  int row0 = b * 1024 + scnk * 16;

  {
    int p = tid, r = p >> 3, cc = p & 7;
    gload_lds16(v64t + ((size_t)bh * 4096 + r * 64 + ((cc ^ (r & 7)) * 8)),
                ((char*)vtt) + p * 16);
    p = tid + 256; r = p >> 3; cc = p & 7;
    gload_lds16(v64t + ((size_t)bh * 4096 + r * 64 + ((cc ^ (r & 7)) * 8)),
                ((char*)vtt) + p * 16);
  }
  for (int idx = tid; idx < 512; idx += 256) {
    int s = idx >> 5, j = (idx & 31) + 32;
    qE[s][j] = 0;
  }
  {
    if (tid < 128) {
      int s = tid >> 3, c = tid & 7;
      size_t grow = ((size_t)(row0 + s)) * 1024 + h * 64;
      *(f32x4*)&qE[s][c * 4] = *(const f32x4*)&qk[grow + c * 8];
    } else {
      int t2 = tid - 128;
      int s = t2 >> 3, c = t2 & 7;
      size_t grow = ((size_t)(row0 + s)) * 1024 + 512 + h * 64;
      *(f32x4*)&kp[s][c * 4] = *(const f32x4*)&qk[grow + c * 8];
    }
  }
  if (tid < 64) Vs[tid] = vsum[b * 512 + h * 64 + tid];
  __syncthreads();
  for (int idx = tid; idx < 512; idx += 256) {
    int s = idx >> 5, j = idx & 31;
    u32 a = qE[s][j], b2 = qE[s][j + 1];
    qO[s][j] = (a >> 16) | (b2 << 16);
    qO[s][j + 32] = 0;
  }
  __syncthreads();
  for (int i = 0; i < 4; ++i) {
    int s = wid * 4 + i;
    u32x4 kk4[8];
#pragma unroll
    for (int u = 0; u < 8; ++u) kk4[u] = *(const u32x4*)&kp[s][u * 4];
    int t = lane, sel = t & 1;
    const u32* qptr = (sel ? qO[s] : qE[s]) + (t >> 1);
    float c = 0.f;
#pragma unroll
    for (int u = 0; u < 8; ++u) {
#pragma unroll
      for (int v = 0; v < 4; ++v) c = dot2h(qptr[u * 4 + v], kk4[u][v], c);
    }
    float sc = c * 0.125f;  // 1/sqrt(64)
    float mx = fmaxf(sc, 0.f);
#pragma unroll
    for (int off = 32; off >= 1; off >>= 1) mx = fmaxf(mx, __shfl_xor(mx, off));
    float w = __expf(sc - mx), wz = __expf(-mx);
    float sw = w;
#pragma unroll
    for (int off = 32; off >= 1; off >>= 1) sw += __shfl_xor(sw, off);
    float inv = 1.f / (sw + 960.f * wz);
    *(u16*)(((char*)&coef[s][0]) + ((2 * t) ^ ((s & 7) << 4))) = f2bf((w - wz) * inv);
    if (lane == 0) zc[s] = wz * inv;
  }
  __syncthreads();
  {
    int la = lane & 15, lg = lane >> 4;
    int r = la;
    int n0 = wid * 16 + la;
    f32x4 a0 = {};
#pragma unroll
    for (int ks = 0; ks < 2; ++ks) {
      int lr = ks * 4 + lg;
      bf16x8 af = *(const bf16x8*)(((const char*)coef) + r * 128 + ((lr ^ (r & 7)) << 4));
      bf16x8 b0 = *(const bf16x8*)(((const char*)vtt) + n0 * 128 + ((lr ^ (n0 & 7)) << 4));
      a0 = __builtin_amdgcn_mfma_f32_16x16x32_bf16(af, b0, a0, 0, 0, 0);
    }
    int srl0 = lg * 4;
    float vs0 = Vs[wid * 16 + la];
#pragma unroll
    for (int j = 0; j < 4; ++j) {
      size_t rb = (size_t)(row0 + srl0 + j) * 512 + h * 64;
      attn_bf[rb + wid * 16 + la] = f2bf(a0[j] + zc[srl0 + j] * vs0);
    }
  }
}

// ---------------- reductions ------------------------------------------------
__device__ __forceinline__ void block_reduce_2(float& a, float& b, float* sbuf) {
  int tid = threadIdx.x, wid = tid >> 6, lane = tid & 63;
#pragma unroll
  for (int off = 32; off >= 1; off >>= 1) {
    a += __shfl_xor(a, off);
    b += __shfl_xor(b, off);
  }
  if (lane == 0) {
    sbuf[wid] = a;
    sbuf[4 + wid] = b;
  }
  __syncthreads();
  a = sbuf[0] + sbuf[1] + sbuf[2] + sbuf[3];
  b = sbuf[4] + sbuf[5] + sbuf[6] + sbuf[7];
  __syncthreads();
}

// out1 = LN(xa + xb + res; g, be); all bf16; writes bf16 IN-PLACE over res.
__global__ __launch_bounds__(256) void ln_res_kernel(
    const u16* __restrict__ xa, const u16* __restrict__ xb,
    u16* __restrict__ res_out,
    const float* __restrict__ g, const float* __restrict__ be) {
  __shared__ float sbuf[8];
  int row = blockIdx.x, tid = threadIdx.x;
  int d = tid * 2;
  size_t base = (size_t)row * 512 + d;
  u32 pa = *(const u32*)&xa[base];
  u32 pb = *(const u32*)&xb[base];
  u32 pr = *(const u32*)&res_out[base];
  float v0 = bf2f((u16)pa) + bf2f((u16)pb) + bf2f((u16)pr);
  float v1 = bf2f((u16)(pa >> 16)) + bf2f((u16)(pb >> 16)) + bf2f((u16)(pr >> 16));
  float s = v0 + v1, q = v0 * v0 + v1 * v1;
  block_reduce_2(s, q, sbuf);
  float mean = s * (1.f / 512.f);
  float var = q * (1.f / 512.f) - mean * mean;
  float rs = rsqrtf(var + 1e-6f);
  float2 gg = *(const float2*)&g[d];
  float2 bb = *(const float2*)&be[d];
  float o0 = (v0 - mean) * rs * gg.x + bb.x;
  float o1 = (v1 - mean) * rs * gg.y + bb.y;
  *(u32*)&res_out[base] = (u32)f2bf(o0) | ((u32)f2bf(o1) << 16);
}

// out = LN3( LN2(out1+fa+fb;g2,be2) + x ; g3,be3 ). out1/fa/fb bf16.
__global__ __launch_bounds__(256) void final_kernel(
    const u16* __restrict__ out1, const u16* __restrict__ fa,
    const u16* __restrict__ fb, const float* __restrict__ x,
    const float* __restrict__ g2, const float* __restrict__ be2,
    const float* __restrict__ g3, const float* __restrict__ be3,
    float* __restrict__ out) {
  __shared__ float sbuf[8];
  int row = blockIdx.x, tid = threadIdx.x;
  int d = tid * 2;
  size_t base = (size_t)row * 512 + d;
  u32 po = *(const u32*)&out1[base];
  u32 pa = *(const u32*)&fa[base];
  u32 pb = *(const u32*)&fb[base];
  float t0 = bf2f((u16)po) + bf2f((u16)pa) + bf2f((u16)pb);
  float t1 = bf2f((u16)(po >> 16)) + bf2f((u16)(pa >> 16)) + bf2f((u16)(pb >> 16));
  float s = t0 + t1, q = t0 * t0 + t1 * t1;
  block_reduce_2(s, q, sbuf);
  float mean = s * (1.f / 512.f);
  float var = q * (1.f / 512.f) - mean * mean;
  float rs = rsqrtf(var + 1e-6f);
  float2 g2v = *(const float2*)&g2[d];
  float2 b2v = *(const float2*)&be2[d];
  float2 xv = *(const float2*)&x[base];
  float y0 = (t0 - mean) * rs * g2v.x + b2v.x + xv.x;
  float y1 = (t1 - mean) * rs * g2v.y + b2v.y + xv.y;
  s = y0 + y1;
  q = y0 * y0 + y1 * y1;
  block_reduce_2(s, q, sbuf);
  mean = s * (1.f / 512.f);
  var = q * (1.f / 512.f) - mean * mean;
  rs = rsqrtf(var + 1e-6f);
  float2 g3v = *(const float2*)&g3[d];
  float2 b3v = *(const float2*)&be3[d];
  float2 o = make_float2((y0 - mean) * rs * g3v.x + b3v.x,
                         (y1 - mean) * rs * g3v.y + b3v.y);
  *(float2*)&out[base] = o;
}

// ---------------------------------------------------------------------------
extern "C" void kernel_launch(void* const* d_in, const int* in_sizes, int n_in,
                              void* d_out, int out_size, void* d_ws, size_t ws_size,
                              hipStream_t stream) {
  const float* x = (const float*)d_in[0];
  const float* wq = (const float*)d_in[1];
  const float* bq = (const float*)d_in[2];
  const float* wk = (const float*)d_in[3];
  const float* bk = (const float*)d_in[4];
  const float* wv = (const float*)d_in[5];
  const float* bv = (const float*)d_in[6];
  const float* wo = (const float*)d_in[7];
  const float* bo = (const float*)d_in[8];
  const float* w1 = (const float*)d_in[9];
  const float* b1 = (const float*)d_in[10];
  const float* w2 = (const float*)d_in[11];
  const float* b2 = (const float*)d_in[12];
  const float* g1 = (const float*)d_in[13];
  const float* be1 = (const float*)d_in[14];
  const float* g2 = (const float*)d_in[15];
  const float* be2 = (const float*)d_in[16];
  const float* g3 = (const float*)d_in[17];
  const float* be3 = (const float*)d_in[18];
  float* out = (float*)d_out;

  const size_t MS = 8192ull * 512ull;
  float* srow = (float*)d_ws;           // 8*512
  float* vsumb = srow + 4096;           // 8*512
  float* qkbias = vsumb + 4096;         // 1024
  u16* qk_f16 = (u16*)(qkbias + 1024);  // 8192*1024 f16; later 2x FFN2 partials
  u16* hidden = qk_f16 + 8192ull * 1024;   // 8192*2048 bf16
  u16* seas_bf = hidden + 8192ull * 2048;  // MS bf16; ln_res overwrites -> out1
  u16* attn_bf = seas_bf + MS;             // MS bf16
  u16* wo0 = attn_bf + MS;                 // WO partial z=0 (bf16)
  u16* wo1 = wo0 + MS;                     // WO partial z=1
  u16* v64t = wo1 + MS;                    // 64*64*64
  u16* a64_bf = v64t + 512 * 512;          // 512*512
  u16* wqkt = a64_bf + 512 * 512;          // [1024,512]
  u16* wvt = wqkt + 1024 * 512;
  u16* wot = wvt + 512 * 512;
  u16* w1t = wot + 512 * 512;       // [2048,512]
  u16* w2t = w1t + 2048ull * 512;   // [512,2048]
  u16* ff0 = qk_f16;                // FFN2 partial z=0 (qk dead after attn)
  u16* ff1 = ff0 + MS;              // FFN2 partial z=1

  hipMemsetAsync(srow, 0, 4096 * sizeof(float), stream);
  prep_kernel<<<4100, 256, 0, stream>>>(
      wq, wk, wv, wo, w1, w2, bq, bk, wqkt, wvt, wot, w1t, w2t, qkbias,
      x, seas_bf, a64_bf, srow);
  vsum_kernel<<<16, 256, 0, stream>>>(srow, wv, bv, vsumb);

  // fused QK projection (f16 out) + V projection (bf16, transposed scatter)
  gemm8p_kernel<0, 2, 1><<<dim3(32, 8), 512, 0, stream>>>(
      seas_bf, wqkt, qkbias, qk_f16, nullptr, 8192, 1024, 512);
  gemm_v_kernel<<<dim3(4, 8), 256, 0, stream>>>(a64_bf, wvt, bv, v64t, 512, 512, 512);

  attn_mfma_kernel<<<4096, 256, 0, stream>>>(qk_f16, v64t, vsumb, attn_bf);

  // WO projection, split-K=2, bf16 partials
  gemm8p_kernel<0, 1, 2><<<dim3(32, 4, 2), 512, 0, stream>>>(
      attn_bf, wot, bo, wo0, wo1, 8192, 512, 512);
  // out1 = LN(wo0+wo1+seasonal) written in-place over seas_bf
  ln_res_kernel<<<8192, 256, 0, stream>>>(wo0, wo1, seas_bf, g1, be1);

  // FFN1 at 256x256 tile: grid (32,8) = one exact fill
  gemm256_kernel<1><<<dim3(32, 8), 512, 0, stream>>>(
      seas_bf, w1t, b1, hidden, 8192, 2048, 512);
  // FFN2, split-K=2, bf16 partials
  gemm8p_kernel<0, 1, 2><<<dim3(32, 4, 2), 512, 0, stream>>>(
      hidden, w2t, b2, ff0, ff1, 8192, 512, 2048);

  final_kernel<<<8192, 256, 0, stream>>>(seas_bf, ff0, ff1, x, g2, be2, g3, be3, out);
}

// Round 15
// 199.146 us; speedup vs baseline: 1.0220x; 1.0220x over previous
//
#include <hip/hip_runtime.h>
#include <cstdint>

// Autoformer encoder block, B=8 S=1024 D=512 H=8 dp=64, K=25 moving avg.
// Math simplifications (exact):
//  - depth-axis FFT autocorr == 64-lag linear correlation; softmax has 960
//    zero logits -> collapsed weighted sum over 64 lags + Vsum rank-1 term.
//  - trend2 cancels; seasonal_init + trend_init == x.
// R15: FFN1/FFN2 on a fine-phase 256x256 kernel (m201-family): 2 dbufs x 2
// ksub planes, 4 phases/K-tile, per-phase {ds_read || 1 stage-unit ->
// barrier -> lgkmcnt(0) -> 16 MFMA -> barrier}, vmcnt(4) at phases 1,3 only.
// FFN2 split-K=4 for exact grid fill (4 bf16 partials summed in final).

typedef float f32x4 __attribute__((ext_vector_type(4)));
typedef __bf16 bf16x8 __attribute__((ext_vector_type(8)));
typedef _Float16 h2t __attribute__((ext_vector_type(2)));
typedef unsigned short u16;
typedef unsigned int u32;
typedef u32 u32x4 __attribute__((ext_vector_type(4)));

__device__ __forceinline__ u16 f2bf(float f) {
  unsigned int u = __float_as_uint(f);
  u = (u + 0x7FFFu + ((u >> 16) & 1u)) >> 16;
  return (u16)u;
}

__device__ __forceinline__ float bf2f(u16 b) { return __uint_as_float((u32)b << 16); }

__device__ __forceinline__ u16 f2h(float f) {
  _Float16 hv = (_Float16)f;
  u16 b;
  __builtin_memcpy(&b, &hv, 2);
  return b;
}

__device__ __forceinline__ float dot2h(u32 qp, u32 kp_, float c) {
#if __has_builtin(__builtin_amdgcn_fdot2)
  return __builtin_amdgcn_fdot2(__builtin_bit_cast(h2t, qp),
                                __builtin_bit_cast(h2t, kp_), c, false);
#else
  h2t q = __builtin_bit_cast(h2t, qp), k = __builtin_bit_cast(h2t, kp_);
  c = fmaf((float)q.x, (float)k.x, c);
  return fmaf((float)q.y, (float)k.y, c);
#endif
}

__device__ __forceinline__ void gload_lds16(const void* g, void* l) {
  __builtin_amdgcn_global_load_lds((__attribute__((address_space(1))) void*)g,
                                   (__attribute__((address_space(3))) void*)l,
                                   16, 0, 0);
}

// ======= merged prep: weight transposes + bias concat + moving average =====
__global__ __launch_bounds__(256) void prep_kernel(
    const float* __restrict__ wq, const float* __restrict__ wk,
    const float* __restrict__ wv, const float* __restrict__ wo,
    const float* __restrict__ w1, const float* __restrict__ w2,
    const float* __restrict__ bq, const float* __restrict__ bk,
    u16* __restrict__ wqkt, u16* __restrict__ wvt, u16* __restrict__ wot,
    u16* __restrict__ w1t, u16* __restrict__ w2t, float* __restrict__ qkbias,
    const float* __restrict__ x, u16* __restrict__ seas_bf,
    u16* __restrict__ a64, float* __restrict__ srow) {
  __shared__ float tile[32][33];
  int i = blockIdx.x;
  int tid = threadIdx.x;
  int tx = tid & 31, ty = tid >> 5;
  if (i >= 3076) {
    int blk = i - 3076;
    int sc = blk & 127, b = blk >> 7;
    int d = tid * 2;
    const float* xb = x + (size_t)b * 1024 * 512 + d;
    int s0 = sc * 8;
    int lo = max(s0 - 12, 0), hi = min(s0 + 12, 1023);
    float sx = 0.f, sy = 0.f;
    for (int j = lo; j <= hi; ++j) {
      float2 v = *(const float2*)&xb[(size_t)j * 512];
      sx += v.x;
      sy += v.y;
    }
    float ax = 0.f, ay = 0.f;
#pragma unroll
    for (int s = s0; s < s0 + 8; ++s) {
      int l2 = max(s - 12, 0), h2 = min(s + 12, 1023);
      float invc = 1.f / (float)(h2 - l2 + 1);
      float2 xv = *(const float2*)&xb[(size_t)s * 512];
      float sex = xv.x - sx * invc;
      float sey = xv.y - sy * invc;
      size_t idx = (size_t)(b * 1024 + s) * 512 + d;
      u32 pk = (u32)f2bf(sex) | ((u32)f2bf(sey) << 16);
      *(u32*)&seas_bf[idx] = pk;
      if (s < 64) *(u32*)&a64[(size_t)(b * 64 + s) * 512 + d] = pk;
      ax += sex;
      ay += sey;
      if (s - 12 >= 0) {
        float2 v = *(const float2*)&xb[(size_t)(s - 12) * 512];
        sx -= v.x;
        sy -= v.y;
      }
      if (s + 13 <= 1023) {
        float2 v = *(const float2*)&xb[(size_t)(s + 13) * 512];
        sx += v.x;
        sy += v.y;
      }
    }
    atomicAdd(&srow[b * 512 + d], ax);
    atomicAdd(&srow[b * 512 + d + 1], ay);
    return;
  }
  if (i >= 3072) {
    int idx = (i - 3072) * 256 + tid;
    qkbias[idx] = idx < 512 ? bq[idx] : bk[idx - 512];
    return;
  }
  const float* src;
  u16* dst;
  int R, C, bx, by;
  if (i < 1024) {
    int w = i >> 8, l = i & 255;
    src = (w == 0 ? wq : w == 1 ? wk : w == 2 ? wv : wo);
    dst = (w == 0 ? wqkt : w == 1 ? wqkt + 512 * 512 : w == 2 ? wvt : wot);
    R = 512; C = 512; bx = l & 15; by = l >> 4;
  } else if (i < 2048) {
    int l = i - 1024;
    src = w1; dst = w1t; R = 512; C = 2048; bx = l & 15; by = l >> 4;
  } else {
    int l = i - 2048;
    src = w2; dst = w2t; R = 2048; C = 512; bx = l & 63; by = l >> 6;
  }
  int r0 = bx * 32, c0 = by * 32;
#pragma unroll
  for (int k = 0; k < 4; ++k)
    tile[ty + 8 * k][tx] = src[(size_t)(r0 + ty + 8 * k) * C + c0 + tx];
  __syncthreads();
#pragma unroll
  for (int k = 0; k < 4; ++k)
    dst[(size_t)(c0 + ty + 8 * k) * R + r0 + tx] = f2bf(tile[tx][ty + 8 * k]);
}

// ---------------- Vsum[b,n] = srow[b,:] @ wv[:,n] + 1024*bv[n] --------------
__global__ __launch_bounds__(256) void vsum_kernel(
    const float* __restrict__ srow, const float* __restrict__ wv,
    const float* __restrict__ bv, float* __restrict__ vsum) {
  int blk = blockIdx.x;  // 16
  int b = blk >> 1;
  int n = (blk & 1) * 256 + threadIdx.x;
  float a0 = 0.f, a1 = 0.f, a2 = 0.f, a3 = 0.f;
  float a4 = 0.f, a5 = 0.f, a6 = 0.f, a7 = 0.f;
  const float* sr = srow + b * 512;
  for (int k = 0; k < 512; k += 8) {
    a0 = fmaf(sr[k + 0], wv[(size_t)(k + 0) * 512 + n], a0);
    a1 = fmaf(sr[k + 1], wv[(size_t)(k + 1) * 512 + n], a1);
    a2 = fmaf(sr[k + 2], wv[(size_t)(k + 2) * 512 + n], a2);
    a3 = fmaf(sr[k + 3], wv[(size_t)(k + 3) * 512 + n], a3);
    a4 = fmaf(sr[k + 4], wv[(size_t)(k + 4) * 512 + n], a4);
    a5 = fmaf(sr[k + 5], wv[(size_t)(k + 5) * 512 + n], a5);
    a6 = fmaf(sr[k + 6], wv[(size_t)(k + 6) * 512 + n], a6);
    a7 = fmaf(sr[k + 7], wv[(size_t)(k + 7) * 512 + n], a7);
  }
  vsum[b * 512 + n] = ((a0 + a1) + (a2 + a3)) + ((a4 + a5) + (a6 + a7)) + 1024.f * bv[n];
}

// ============ 8-phase-family GEMM: 256x128 tile, BK=64, 8 waves =============
// OMODE: 1=bf16, 2=f16. KSPLIT: z>0 -> partial to Cv2 (bias only z==0).
template <int RELU, int OMODE, int KSPLIT>
__global__ __launch_bounds__(512, 1) void gemm8p_kernel(
    const u16* __restrict__ A, const u16* __restrict__ Bt,
    const float* __restrict__ bias, void* __restrict__ Cv, void* __restrict__ Cv2,
    int M, int N, int K) {
  __shared__ u16 As[3][2][256 * 32];
  __shared__ u16 Bs[3][2][128 * 32];
  const int tid = threadIdx.x;
  const int wid = tid >> 6, lane = tid & 63;
  const int wm = wid >> 2, wn = wid & 3;
  const int la = lane & 15, lg = lane >> 4;
  int nwg = gridDim.x * gridDim.y;
  int lin = blockIdx.y * gridDim.x + blockIdx.x;
  int swz = (lin & 7) * (nwg >> 3) + (lin >> 3);
  int bx = swz / gridDim.y, by = swz % gridDim.y;
  const int row0 = bx * 256, col0 = by * 128;
  const int z = (KSPLIT > 1) ? (int)blockIdx.z : 0;
  const int kbeg = z * (K / KSPLIT);
  const int nt = (K / KSPLIT) / 64;
  f32x4 acc[8][2] = {};

  auto stageh = [&](int buf, int h, int k0) {
    int kh = k0 + h * 32;
    {
      int p = tid, r = p >> 2, cg = (p & 3) ^ ((r >> 1) & 3);
      gload_lds16(A + (size_t)(row0 + r) * K + kh + cg * 8,
                  ((char*)&As[buf][h][0]) + p * 16);
    }
    {
      int p = tid + 512, r = p >> 2, cg = (p & 3) ^ ((r >> 1) & 3);
      gload_lds16(A + (size_t)(row0 + r) * K + kh + cg * 8,
                  ((char*)&As[buf][h][0]) + p * 16);
    }
    {
      int p = tid, r = p >> 2, cg = (p & 3) ^ ((r >> 1) & 3);
      gload_lds16(Bt + (size_t)(col0 + r) * K + kh + cg * 8,
                  ((char*)&Bs[buf][h][0]) + p * 16);
    }
  };

  stageh(0, 0, kbeg);
  stageh(0, 1, kbeg);
  stageh(1, 0, kbeg + 64);
  stageh(1, 1, kbeg + 64);
  asm volatile("s_waitcnt vmcnt(6)" ::: "memory");
  __builtin_amdgcn_s_barrier();
  __builtin_amdgcn_sched_barrier(0);

  for (int t = 0; t < nt; ++t) {
    const int buf = t % 3;
    const int nbuf = (t + 2) % 3;
    const bool pre = (t + 2 < nt);
#pragma unroll
    for (int h = 0; h < 2; ++h) {
      bf16x8 af[8], bf[2];
#pragma unroll
      for (int mf = 0; mf < 8; ++mf) {
        int r = wm * 128 + mf * 16 + la;
        int cp = lg ^ ((r >> 1) & 3);
        af[mf] = *(const bf16x8*)&As[buf][h][r * 32 + cp * 8];
      }
#pragma unroll
      for (int nf = 0; nf < 2; ++nf) {
        int r = wn * 32 + nf * 16 + la;
        int cp = lg ^ ((r >> 1) & 3);
        bf[nf] = *(const bf16x8*)&Bs[buf][h][r * 32 + cp * 8];
      }
      if (pre) stageh(nbuf, h, kbeg + (t + 2) * 64);
      __builtin_amdgcn_sched_barrier(0);
      __builtin_amdgcn_s_barrier();
      __builtin_amdgcn_s_setprio(1);
#pragma unroll
      for (int mf = 0; mf < 8; ++mf)
#pragma unroll
        for (int nf = 0; nf < 2; ++nf)
          acc[mf][nf] = __builtin_amdgcn_mfma_f32_16x16x32_bf16(af[mf], bf[nf], acc[mf][nf], 0, 0, 0);
      __builtin_amdgcn_s_setprio(0);
      __builtin_amdgcn_sched_barrier(0);
      if (h == 0) __builtin_amdgcn_s_barrier();
    }
    if (pre)
      asm volatile("s_waitcnt vmcnt(6)" ::: "memory");
    else if (t + 1 < nt)
      asm volatile("s_waitcnt vmcnt(0)" ::: "memory");
    __builtin_amdgcn_s_barrier();
    __builtin_amdgcn_sched_barrier(0);
  }

  void* Cout = (z == 0) ? Cv : Cv2;
#pragma unroll
  for (int mf = 0; mf < 8; ++mf) {
    int r = row0 + wm * 128 + mf * 16 + lg * 4;
#pragma unroll
    for (int nf = 0; nf < 2; ++nf) {
      int cc = col0 + wn * 32 + nf * 16 + la;
      float bvv = (z == 0) ? bias[cc] : 0.f;
#pragma unroll
      for (int j = 0; j < 4; ++j) {
        float v = acc[mf][nf][j] + bvv;
        if (RELU) v = fmaxf(v, 0.f);
        if constexpr (OMODE == 1)
          ((u16*)Cout)[(size_t)(r + j) * N + cc] = f2bf(v);
        else
          ((u16*)Cout)[(size_t)(r + j) * N + cc] = f2h(v);
      }
    }
  }
}

// ====== fine-phase 256x256 GEMM (m201-family), 4 phases per K-tile =========
// 2 dbufs x 2 ksub planes (16 KB units); per phase: {ds_read frags || stage
// one unit (2 gloads)} -> barrier -> lgkmcnt(0) -> setprio+16 MFMA -> barrier.
// vmcnt(4) at end of phases 1,3 (never 0 in steady state).
// Dependency audit: unit staged at t.p0 (A-k0(t+1)) consumed t+1.p0, ensured
// by t.p3's vmcnt(4) (leaves only t.p2,p3 = 4 loads outstanding). k1 units
// (staged t-1.p2/p3) consumed t.p2, ensured by t.p1's vmcnt(4).
// KSPLIT: z>0 -> bf16 partials to Cv[z] (bias only z==0).
template <int RELU, int KSPLIT>
__global__ __launch_bounds__(512, 1) void gemmfp_kernel(
    const u16* __restrict__ A, const u16* __restrict__ Bt,
    const float* __restrict__ bias, u16* __restrict__ C0, u16* __restrict__ C1,
    u16* __restrict__ C2, u16* __restrict__ C3, int M, int N, int K) {
  __shared__ u16 As[2][2][256 * 32];  // dbuf x ksub x (256 rows x 32 cols)
  __shared__ u16 Bs[2][2][256 * 32];
  const int tid = threadIdx.x;
  const int wid = tid >> 6, lane = tid & 63;
  const int wm = wid >> 2, wn = wid & 3;  // 2M x 4N waves; per-wave 128x64
  const int la = lane & 15, lg = lane >> 4;
  int nwg = gridDim.x * gridDim.y;
  int lin = blockIdx.y * gridDim.x + blockIdx.x;
  int swz = (lin & 7) * (nwg >> 3) + (lin >> 3);
  int bx = swz / gridDim.y, by = swz % gridDim.y;
  const int row0 = bx * 256, col0 = by * 256;
  const int z = (KSPLIT > 1) ? (int)blockIdx.z : 0;
  const int kbeg = z * (K / KSPLIT);
  const int nt = (K / KSPLIT) / 64;
  f32x4 acc[8][4] = {};

  auto stageA = [&](int d, int s, int k0) {
#pragma unroll
    for (int j = 0; j < 2; ++j) {
      int p = tid + j * 512;
      int r = p >> 2, cg = (p & 3) ^ ((r >> 1) & 3);
      gload_lds16(A + (size_t)(row0 + r) * K + k0 + s * 32 + cg * 8,
                  ((char*)&As[d][s][0]) + p * 16);
    }
  };
  auto stageB = [&](int d, int s, int k0) {
#pragma unroll
    for (int j = 0; j < 2; ++j) {
      int p = tid + j * 512;
      int r = p >> 2, cg = (p & 3) ^ ((r >> 1) & 3);
      gload_lds16(Bt + (size_t)(col0 + r) * K + k0 + s * 32 + cg * 8,
                  ((char*)&Bs[d][s][0]) + p * 16);
    }
  };

  // prologue: tile 0 fully staged
  stageA(0, 0, kbeg);
  stageB(0, 0, kbeg);
  stageA(0, 1, kbeg);
  stageB(0, 1, kbeg);
  asm volatile("s_waitcnt vmcnt(0)" ::: "memory");
  __builtin_amdgcn_s_barrier();
  __builtin_amdgcn_sched_barrier(0);

  for (int t = 0; t < nt; ++t) {
    const int d = t & 1, nd = d ^ 1;
    const int k1 = kbeg + (t + 1) * 64;
    const bool pre = (t + 1 < nt);
    bf16x8 af[8], bf[2];
#pragma unroll
    for (int s = 0; s < 2; ++s) {
      // ---- phase (s,0): A frags for ksub s + B nf{0,1} ----
#pragma unroll
      for (int mf = 0; mf < 8; ++mf) {
        int r = wm * 128 + mf * 16 + la;
        int cp = lg ^ ((r >> 1) & 3);
        af[mf] = *(const bf16x8*)(((const char*)&As[d][s][0]) + r * 64 + cp * 16);
      }
#pragma unroll
      for (int nf = 0; nf < 2; ++nf) {
        int r = wn * 64 + nf * 16 + la;
        int cp = lg ^ ((r >> 1) & 3);
        bf[nf] = *(const bf16x8*)(((const char*)&Bs[d][s][0]) + r * 64 + cp * 16);
      }
      if (pre) stageA(nd, s, k1);
      __builtin_amdgcn_sched_barrier(0);
      __builtin_amdgcn_s_barrier();
      asm volatile("s_waitcnt lgkmcnt(0)" ::: "memory");
      __builtin_amdgcn_sched_barrier(0);
      __builtin_amdgcn_s_setprio(1);
#pragma unroll
      for (int mf = 0; mf < 8; ++mf)
#pragma unroll
        for (int nf = 0; nf < 2; ++nf)
          acc[mf][nf] = __builtin_amdgcn_mfma_f32_16x16x32_bf16(af[mf], bf[nf], acc[mf][nf], 0, 0, 0);
      __builtin_amdgcn_s_setprio(0);
      __builtin_amdgcn_sched_barrier(0);
      __builtin_amdgcn_s_barrier();
      // ---- phase (s,1): B nf{2,3}, A frags reused ----
#pragma unroll
      for (int nf = 0; nf < 2; ++nf) {
        int r = wn * 64 + (nf + 2) * 16 + la;
        int cp = lg ^ ((r >> 1) & 3);
        bf[nf] = *(const bf16x8*)(((const char*)&Bs[d][s][0]) + r * 64 + cp * 16);
      }
      if (pre) stageB(nd, s, k1);
      __builtin_amdgcn_sched_barrier(0);
      if (pre)
        asm volatile("s_waitcnt vmcnt(4)" ::: "memory");
      else
        asm volatile("s_waitcnt vmcnt(0)" ::: "memory");
      __builtin_amdgcn_s_barrier();
      asm volatile("s_waitcnt lgkmcnt(0)" ::: "memory");
      __builtin_amdgcn_sched_barrier(0);
      __builtin_amdgcn_s_setprio(1);
#pragma unroll
      for (int mf = 0; mf < 8; ++mf)
#pragma unroll
        for (int nf = 0; nf < 2; ++nf)
          acc[mf][nf + 2] = __builtin_amdgcn_mfma_f32_16x16x32_bf16(af[mf], bf[nf], acc[mf][nf + 2], 0, 0, 0);
      __builtin_amdgcn_s_setprio(0);
      __builtin_amdgcn_sched_barrier(0);
      __builtin_amdgcn_s_barrier();
    }
  }

  u16* Cout = (z == 0) ? C0 : (z == 1) ? C1 : (z == 2) ? C2 : C3;
#pragma unroll
  for (int mf = 0; mf < 8; ++mf) {
    int r = row0 + wm * 128 + mf * 16 + lg * 4;
#pragma unroll
    for (int nf = 0; nf < 4; ++nf) {
      int cc = col0 + wn * 64 + nf * 16 + la;
      float bvv = (z == 0) ? bias[cc] : 0.f;
#pragma unroll
      for (int j = 0; j < 4; ++j) {
        float v = acc[mf][nf][j] + bvv;
        if (RELU) v = fmaxf(v, 0.f);
        Cout[(size_t)(r + j) * N + cc] = f2bf(v);
      }
    }
  }
}

// ---------------- small GEMM for V projection (transposed bf16 scatter) -----
__global__ __launch_bounds__(256, 6) void gemm_v_kernel(
    const u16* __restrict__ A, const u16* __restrict__ Bt,
    const float* __restrict__ bias, u16* __restrict__ Cv, int M, int N, int K) {
  constexpr int BK = 32;
  __shared__ u16 As[2][128 * BK];
  __shared__ u16 Bs[2][64 * BK];
  const int tid = threadIdx.x;
  const int wid = tid >> 6, lane = tid & 63;
  const int wm = wid >> 1, wn = wid & 1;
  const int la = lane & 15, lg = lane >> 4;
  const int row0 = blockIdx.x * 128, col0 = blockIdx.y * 64;
  const int ksteps = K / BK;
  f32x4 acc[4][2] = {};

  auto stage = [&](int buf, int k0) {
    {
      int p = tid, r = p >> 2, cg = (p & 3) ^ ((r >> 1) & 3);
      gload_lds16(A + (size_t)(row0 + r) * K + k0 + cg * 8, ((char*)As[buf]) + p * 16);
    }
    {
      int p = tid + 256, r = p >> 2, cg = (p & 3) ^ ((r >> 1) & 3);
      gload_lds16(A + (size_t)(row0 + r) * K + k0 + cg * 8, ((char*)As[buf]) + p * 16);
    }
    {
      int p = tid, r = p >> 2, cg = (p & 3) ^ ((r >> 1) & 3);
      gload_lds16(Bt + (size_t)(col0 + r) * K + k0 + cg * 8, ((char*)Bs[buf]) + p * 16);
    }
  };

  stage(0, 0);
  __syncthreads();
  for (int t = 0; t < ksteps; ++t) {
    const int cur = t & 1;
    if (t + 1 < ksteps) stage(cur ^ 1, (t + 1) * BK);
    bf16x8 af[4], bfr[2];
#pragma unroll
    for (int m = 0; m < 4; ++m) {
      int r = wm * 64 + m * 16 + la;
      int cp = lg ^ ((r >> 1) & 3);
      af[m] = *(const bf16x8*)(((const char*)As[cur]) + r * 64 + cp * 16);
    }
#pragma unroll
    for (int n = 0; n < 2; ++n) {
      int r = wn * 32 + n * 16 + la;
      int cp = lg ^ ((r >> 1) & 3);
      bfr[n] = *(const bf16x8*)(((const char*)Bs[cur]) + r * 64 + cp * 16);
    }
#pragma unroll
    for (int m = 0; m < 4; ++m)
#pragma unroll
      for (int n = 0; n < 2; ++n)
        acc[m][n] = __builtin_amdgcn_mfma_f32_16x16x32_bf16(af[m], bfr[n], acc[m][n], 0, 0, 0);
    __syncthreads();
  }

#pragma unroll
  for (int m = 0; m < 4; ++m) {
    int r = row0 + wm * 64 + m * 16 + lg * 4;
#pragma unroll
    for (int n = 0; n < 2; ++n) {
      int cc = col0 + wn * 32 + n * 16 + la;
      float bvv = bias[cc];
#pragma unroll
      for (int j = 0; j < 4; ++j) {
        float v = acc[m][n][j] + bvv;
        int rr = r + j;
        int bb = rr >> 6, tt = rr & 63, hh = cc >> 6, dd = cc & 63;
        Cv[(((size_t)bb * 8 + hh) * 64 + dd) * 64 + tt] = f2bf(v);
      }
    }
  }
}

// ---------- attention: 64-lag autocorr (f16 dot2) + MFMA PV, 16-row chunks --
__global__ __launch_bounds__(256) void attn_mfma_kernel(
    const u16* __restrict__ qk, const u16* __restrict__ v64t,
    const float* __restrict__ vsum, u16* __restrict__ attn_bf) {
  __shared__ u32 qE[16][64];
  __shared__ u32 qO[16][64];
  __shared__ u32 kp[16][32];
  __shared__ u16 coef[16][64];
  __shared__ u16 vtt[64][64];
  __shared__ float zc[16];
  __shared__ float Vs[64];
  int bid = blockIdx.x;
  int scnk = bid & 63, h = (bid >> 6) & 7, b = bid >> 9;
  int tid = threadIdx.x, wid = tid >> 6, lane = tid & 63;
  int bh = b * 8 + h;
  int row0 = b * 1024 + scnk * 16;

  {
    int p = tid, r = p >> 3, cc = p & 7;
    gload_lds16(v64t + ((size_t)bh * 4096 + r * 64 + ((cc ^ (r & 7)) * 8)),
                ((char*)vtt) + p * 16);
    p = tid + 256; r = p >> 3; cc = p & 7;
    gload_lds16(v64t + ((size_t)bh * 4096 + r * 64 + ((cc ^ (r & 7)) * 8)),
                ((char*)vtt) + p * 16);
  }
  for (int idx = tid; idx < 512; idx += 256) {
    int s = idx >> 5, j = (idx & 31) + 32;
    qE[s][j] = 0;
  }
  {
    if (tid < 128) {
      int s = tid >> 3, c = tid & 7;
      size_t grow = ((size_t)(row0 + s)) * 1024 + h * 64;
      *(f32x4*)&qE[s][c * 4] = *(const f32x4*)&qk[grow + c * 8];
    } else {
      int t2 = tid - 128;
      int s = t2 >> 3, c = t2 & 7;
      size_t grow = ((size_t)(row0 + s)) * 1024 + 512 + h * 64;
      *(f32x4*)&kp[s][c * 4] = *(const f32x4*)&qk[grow + c * 8];
    }
  }
  if (tid < 64) Vs[tid] = vsum[b * 512 + h * 64 + tid];
  __syncthreads();
  for (int idx = tid; idx < 512; idx += 256) {
    int s = idx >> 5, j = idx & 31;
    u32 a = qE[s][j], b2 = qE[s][j + 1];
    qO[s][j] = (a >> 16) | (b2 << 16);
    qO[s][j + 32] = 0;
  }
  __syncthreads();
  for (int i = 0; i < 4; ++i) {
    int s = wid * 4 + i;
    u32x4 kk4[8];
#pragma unroll
    for (int u = 0; u < 8; ++u) kk4[u] = *(const u32x4*)&kp[s][u * 4];
    int t = lane, sel = t & 1;
    const u32* qptr = (sel ? qO[s] : qE[s]) + (t >> 1);
    float c = 0.f;
#pragma unroll
    for (int u = 0; u < 8; ++u) {
#pragma unroll
      for (int v = 0; v < 4; ++v) c = dot2h(qptr[u * 4 + v], kk4[u][v], c);
    }
    float sc = c * 0.125f;  // 1/sqrt(64)
    float mx = fmaxf(sc, 0.f);
#pragma unroll
    for (int off = 32; off >= 1; off >>= 1) mx = fmaxf(mx, __shfl_xor(mx, off));
    float w = __expf(sc - mx), wz = __expf(-mx);
    float sw = w;
#pragma unroll
    for (int off = 32; off >= 1; off >>= 1) sw += __shfl_xor(sw, off);
    float inv = 1.f / (sw + 960.f * wz);
    *(u16*)(((char*)&coef[s][0]) + ((2 * t) ^ ((s & 7) << 4))) = f2bf((w - wz) * inv);
    if (lane == 0) zc[s] = wz * inv;
  }
  __syncthreads();
  {
    int la = lane & 15, lg = lane >> 4;
    int r = la;
    int n0 = wid * 16 + la;
    f32x4 a0 = {};
#pragma unroll
    for (int ks = 0; ks < 2; ++ks) {
      int lr = ks * 4 + lg;
      bf16x8 af = *(const bf16x8*)(((const char*)coef) + r * 128 + ((lr ^ (r & 7)) << 4));
      bf16x8 b0 = *(const bf16x8*)(((const char*)vtt) + n0 * 128 + ((lr ^ (n0 & 7)) << 4));
      a0 = __builtin_amdgcn_mfma_f32_16x16x32_bf16(af, b0, a0, 0, 0, 0);
    }
    int srl0 = lg * 4;
    float vs0 = Vs[wid * 16 + la];
#pragma unroll
    for (int j = 0; j < 4; ++j) {
      size_t rb = (size_t)(row0 + srl0 + j) * 512 + h * 64;
      attn_bf[rb + wid * 16 + la] = f2bf(a0[j] + zc[srl0 + j] * vs0);
    }
  }
}

// ---------------- reductions ------------------------------------------------
__device__ __forceinline__ void block_reduce_2(float& a, float& b, float* sbuf) {
  int tid = threadIdx.x, wid = tid >> 6, lane = tid & 63;
#pragma unroll
  for (int off = 32; off >= 1; off >>= 1) {
    a += __shfl_xor(a, off);
    b += __shfl_xor(b, off);
  }
  if (lane == 0) {
    sbuf[wid] = a;
    sbuf[4 + wid] = b;
  }
  __syncthreads();
  a = sbuf[0] + sbuf[1] + sbuf[2] + sbuf[3];
  b = sbuf[4] + sbuf[5] + sbuf[6] + sbuf[7];
  __syncthreads();
}

// out1 = LN(xa + xb + res; g, be); all bf16; writes bf16 IN-PLACE over res.
__global__ __launch_bounds__(256) void ln_res_kernel(
    const u16* __restrict__ xa, const u16* __restrict__ xb,
    u16* __restrict__ res_out,
    const float* __restrict__ g, const float* __restrict__ be) {
  __shared__ float sbuf[8];
  int row = blockIdx.x, tid = threadIdx.x;
  int d = tid * 2;
  size_t base = (size_t)row * 512 + d;
  u32 pa = *(const u32*)&xa[base];
  u32 pb = *(const u32*)&xb[base];
  u32 pr = *(const u32*)&res_out[base];
  float v0 = bf2f((u16)pa) + bf2f((u16)pb) + bf2f((u16)pr);
  float v1 = bf2f((u16)(pa >> 16)) + bf2f((u16)(pb >> 16)) + bf2f((u16)(pr >> 16));
  float s = v0 + v1, q = v0 * v0 + v1 * v1;
  block_reduce_2(s, q, sbuf);
  float mean = s * (1.f / 512.f);
  float var = q * (1.f / 512.f) - mean * mean;
  float rs = rsqrtf(var + 1e-6f);
  float2 gg = *(const float2*)&g[d];
  float2 bb = *(const float2*)&be[d];
  float o0 = (v0 - mean) * rs * gg.x + bb.x;
  float o1 = (v1 - mean) * rs * gg.y + bb.y;
  *(u32*)&res_out[base] = (u32)f2bf(o0) | ((u32)f2bf(o1) << 16);
}

// out = LN3( LN2(out1+fa+fb+fc+fd;g2,be2) + x ; g3,be3 ). all bf16 partials.
__global__ __launch_bounds__(256) void final_kernel(
    const u16* __restrict__ out1, const u16* __restrict__ fa,
    const u16* __restrict__ fb, const u16* __restrict__ fc,
    const u16* __restrict__ fd, const float* __restrict__ x,
    const float* __restrict__ g2, const float* __restrict__ be2,
    const float* __restrict__ g3, const float* __restrict__ be3,
    float* __restrict__ out) {
  __shared__ float sbuf[8];
  int row = blockIdx.x, tid = threadIdx.x;
  int d = tid * 2;
  size_t base = (size_t)row * 512 + d;
  u32 po = *(const u32*)&out1[base];
  u32 pa = *(const u32*)&fa[base];
  u32 pb = *(const u32*)&fb[base];
  u32 pc = *(const u32*)&fc[base];
  u32 pd = *(const u32*)&fd[base];
  float t0 = bf2f((u16)po) + bf2f((u16)pa) + bf2f((u16)pb) + bf2f((u16)pc) + bf2f((u16)pd);
  float t1 = bf2f((u16)(po >> 16)) + bf2f((u16)(pa >> 16)) + bf2f((u16)(pb >> 16)) +
             bf2f((u16)(pc >> 16)) + bf2f((u16)(pd >> 16));
  float s = t0 + t1, q = t0 * t0 + t1 * t1;
  block_reduce_2(s, q, sbuf);
  float mean = s * (1.f / 512.f);
  float var = q * (1.f / 512.f) - mean * mean;
  float rs = rsqrtf(var + 1e-6f);
  float2 g2v = *(const float2*)&g2[d];
  float2 b2v = *(const float2*)&be2[d];
  float2 xv = *(const float2*)&x[base];
  float y0 = (t0 - mean) * rs * g2v.x + b2v.x + xv.x;
  float y1 = (t1 - mean) * rs * g2v.y + b2v.y + xv.y;
  s = y0 + y1;
  q = y0 * y0 + y1 * y1;
  block_reduce_2(s, q, sbuf);
  mean = s * (1.f / 512.f);
  var = q * (1.f / 512.f) - mean * mean;
  rs = rsqrtf(var + 1e-6f);
  float2 g3v = *(const float2*)&g3[d];
  float2 b3v = *(const float2*)&be3[d];
  float2 o = make_float2((y0 - mean) * rs * g3v.x + b3v.x,
                         (y1 - mean) * rs * g3v.y + b3v.y);
  *(float2*)&out[base] = o;
}

// ---------------------------------------------------------------------------
extern "C" void kernel_launch(void* const* d_in, const int* in_sizes, int n_in,
                              void* d_out, int out_size, void* d_ws, size_t ws_size,
                              hipStream_t stream) {
  const float* x = (const float*)d_in[0];
  const float* wq = (const float*)d_in[1];
  const float* bq = (const float*)d_in[2];
  const float* wk = (const float*)d_in[3];
  const float* bk = (const float*)d_in[4];
  const float* wv = (const float*)d_in[5];
  const float* bv = (const float*)d_in[6];
  const float* wo = (const float*)d_in[7];
  const float* bo = (const float*)d_in[8];
  const float* w1 = (const float*)d_in[9];
  const float* b1 = (const float*)d_in[10];
  const float* w2 = (const float*)d_in[11];
  const float* b2 = (const float*)d_in[12];
  const float* g1 = (const float*)d_in[13];
  const float* be1 = (const float*)d_in[14];
  const float* g2 = (const float*)d_in[15];
  const float* be2 = (const float*)d_in[16];
  const float* g3 = (const float*)d_in[17];
  const float* be3 = (const float*)d_in[18];
  float* out = (float*)d_out;

  const size_t MS = 8192ull * 512ull;
  float* srow = (float*)d_ws;           // 8*512
  float* vsumb = srow + 4096;           // 8*512
  float* qkbias = vsumb + 4096;         // 1024
  u16* qk_f16 = (u16*)(qkbias + 1024);  // 8192*1024 f16; later FFN2 partials 0,1
  u16* hidden = qk_f16 + 8192ull * 1024;   // 8192*2048 bf16
  u16* seas_bf = hidden + 8192ull * 2048;  // MS bf16; ln_res overwrites -> out1
  u16* attn_bf = seas_bf + MS;             // MS bf16
  u16* wo0 = attn_bf + MS;                 // WO partial z=0; later FFN2 partial 2
  u16* wo1 = wo0 + MS;                     // WO partial z=1; later FFN2 partial 3
  u16* v64t = wo1 + MS;                    // 64*64*64
  u16* a64_bf = v64t + 512 * 512;          // 512*512
  u16* wqkt = a64_bf + 512 * 512;          // [1024,512]
  u16* wvt = wqkt + 1024 * 512;
  u16* wot = wvt + 512 * 512;
  u16* w1t = wot + 512 * 512;       // [2048,512]
  u16* w2t = w1t + 2048ull * 512;   // [512,2048]
  u16* ff0 = qk_f16;                // FFN2 partials (qk dead after attn,
  u16* ff1 = ff0 + MS;              //  wo0/wo1 dead after ln_res)
  u16* ff2 = wo0;
  u16* ff3 = wo1;

  hipMemsetAsync(srow, 0, 4096 * sizeof(float), stream);
  prep_kernel<<<4100, 256, 0, stream>>>(
      wq, wk, wv, wo, w1, w2, bq, bk, wqkt, wvt, wot, w1t, w2t, qkbias,
      x, seas_bf, a64_bf, srow);
  vsum_kernel<<<16, 256, 0, stream>>>(srow, wv, bv, vsumb);

  // fused QK projection (f16 out) + V projection (bf16, transposed scatter)
  gemm8p_kernel<0, 2, 1><<<dim3(32, 8), 512, 0, stream>>>(
      seas_bf, wqkt, qkbias, qk_f16, nullptr, 8192, 1024, 512);
  gemm_v_kernel<<<dim3(4, 8), 256, 0, stream>>>(a64_bf, wvt, bv, v64t, 512, 512, 512);

  attn_mfma_kernel<<<4096, 256, 0, stream>>>(qk_f16, v64t, vsumb, attn_bf);

  // WO projection, split-K=2, bf16 partials
  gemm8p_kernel<0, 1, 2><<<dim3(32, 4, 2), 512, 0, stream>>>(
      attn_bf, wot, bo, wo0, wo1, 8192, 512, 512);
  // out1 = LN(wo0+wo1+seasonal) written in-place over seas_bf
  ln_res_kernel<<<8192, 256, 0, stream>>>(wo0, wo1, seas_bf, g1, be1);

  // FFN1: fine-phase 256x256, grid (32,8) = exact fill
  gemmfp_kernel<1, 1><<<dim3(32, 8), 512, 0, stream>>>(
      seas_bf, w1t, b1, hidden, nullptr, nullptr, nullptr, 8192, 2048, 512);
  // FFN2: fine-phase 256x256, split-K=4 -> (32,2,4) = 256 blocks
  gemmfp_kernel<0, 4><<<dim3(32, 2, 4), 512, 0, stream>>>(
      hidden, w2t, b2, ff0, ff1, ff2, ff3, 8192, 512, 2048);

  final_kernel<<<8192, 256, 0, stream>>>(seas_bf, ff0, ff1, ff2, ff3, x,
                                         g2, be2, g3, be3, out);
}

// Round 16
// 182.310 us; speedup vs baseline: 1.1164x; 1.0923x over previous
//
#include <hip/hip_runtime.h>
#include <cstdint>

// Autoformer encoder block, B=8 S=1024 D=512 H=8 dp=64, K=25 moving avg.
// Math simplifications (exact):
//  - depth-axis FFT autocorr == 64-lag linear correlation; softmax has 960
//    zero logits -> collapsed weighted sum over 64 lags + Vsum rank-1 term.
//  - trend2 cancels; seasonal_init + trend_init == x.
// R16: QK-GEMM + V-GEMM + vsum merged into one launch (small jobs hide under
// QK); movavg writes per-chunk srow partials (no atomics, no memset).
// 8 launches total.

typedef float f32x4 __attribute__((ext_vector_type(4)));
typedef __bf16 bf16x8 __attribute__((ext_vector_type(8)));
typedef _Float16 h2t __attribute__((ext_vector_type(2)));
typedef unsigned short u16;
typedef unsigned int u32;
typedef u32 u32x4 __attribute__((ext_vector_type(4)));

__device__ __forceinline__ u16 f2bf(float f) {
  unsigned int u = __float_as_uint(f);
  u = (u + 0x7FFFu + ((u >> 16) & 1u)) >> 16;
  return (u16)u;
}

__device__ __forceinline__ float bf2f(u16 b) { return __uint_as_float((u32)b << 16); }

__device__ __forceinline__ u16 f2h(float f) {
  _Float16 hv = (_Float16)f;
  u16 b;
  __builtin_memcpy(&b, &hv, 2);
  return b;
}

__device__ __forceinline__ float dot2h(u32 qp, u32 kp_, float c) {
#if __has_builtin(__builtin_amdgcn_fdot2)
  return __builtin_amdgcn_fdot2(__builtin_bit_cast(h2t, qp),
                                __builtin_bit_cast(h2t, kp_), c, false);
#else
  h2t q = __builtin_bit_cast(h2t, qp), k = __builtin_bit_cast(h2t, kp_);
  c = fmaf((float)q.x, (float)k.x, c);
  return fmaf((float)q.y, (float)k.y, c);
#endif
}

__device__ __forceinline__ void gload_lds16(const void* g, void* l) {
  __builtin_amdgcn_global_load_lds((__attribute__((address_space(1))) void*)g,
                                   (__attribute__((address_space(3))) void*)l,
                                   16, 0, 0);
}

// ======= merged prep: weight transposes + bias concat + moving average =====
__global__ __launch_bounds__(256) void prep_kernel(
    const float* __restrict__ wq, const float* __restrict__ wk,
    const float* __restrict__ wv, const float* __restrict__ wo,
    const float* __restrict__ w1, const float* __restrict__ w2,
    const float* __restrict__ bq, const float* __restrict__ bk,
    u16* __restrict__ wqkt, u16* __restrict__ wvt, u16* __restrict__ wot,
    u16* __restrict__ w1t, u16* __restrict__ w2t, float* __restrict__ qkbias,
    const float* __restrict__ x, u16* __restrict__ seas_bf,
    u16* __restrict__ a64, float* __restrict__ srow_part) {
  __shared__ float tile[32][33];
  int i = blockIdx.x;
  int tid = threadIdx.x;
  int tx = tid & 31, ty = tid >> 5;
  if (i >= 3076) {
    int blk = i - 3076;
    int sc = blk & 127, b = blk >> 7;
    int d = tid * 2;
    const float* xb = x + (size_t)b * 1024 * 512 + d;
    int s0 = sc * 8;
    int lo = max(s0 - 12, 0), hi = min(s0 + 12, 1023);
    float sx = 0.f, sy = 0.f;
    for (int j = lo; j <= hi; ++j) {
      float2 v = *(const float2*)&xb[(size_t)j * 512];
      sx += v.x;
      sy += v.y;
    }
    float ax = 0.f, ay = 0.f;
#pragma unroll
    for (int s = s0; s < s0 + 8; ++s) {
      int l2 = max(s - 12, 0), h2 = min(s + 12, 1023);
      float invc = 1.f / (float)(h2 - l2 + 1);
      float2 xv = *(const float2*)&xb[(size_t)s * 512];
      float sex = xv.x - sx * invc;
      float sey = xv.y - sy * invc;
      size_t idx = (size_t)(b * 1024 + s) * 512 + d;
      u32 pk = (u32)f2bf(sex) | ((u32)f2bf(sey) << 16);
      *(u32*)&seas_bf[idx] = pk;
      if (s < 64) *(u32*)&a64[(size_t)(b * 64 + s) * 512 + d] = pk;
      ax += sex;
      ay += sey;
      if (s - 12 >= 0) {
        float2 v = *(const float2*)&xb[(size_t)(s - 12) * 512];
        sx -= v.x;
        sy -= v.y;
      }
      if (s + 13 <= 1023) {
        float2 v = *(const float2*)&xb[(size_t)(s + 13) * 512];
        sx += v.x;
        sy += v.y;
      }
    }
    // per-chunk partial: no atomics, every slot written exactly once
    *(float2*)&srow_part[(size_t)sc * 4096 + b * 512 + d] = make_float2(ax, ay);
    return;
  }
  if (i >= 3072) {
    int idx = (i - 3072) * 256 + tid;
    qkbias[idx] = idx < 512 ? bq[idx] : bk[idx - 512];
    return;
  }
  const float* src;
  u16* dst;
  int R, C, bx, by;
  if (i < 1024) {
    int w = i >> 8, l = i & 255;
    src = (w == 0 ? wq : w == 1 ? wk : w == 2 ? wv : wo);
    dst = (w == 0 ? wqkt : w == 1 ? wqkt + 512 * 512 : w == 2 ? wvt : wot);
    R = 512; C = 512; bx = l & 15; by = l >> 4;
  } else if (i < 2048) {
    int l = i - 1024;
    src = w1; dst = w1t; R = 512; C = 2048; bx = l & 15; by = l >> 4;
  } else {
    int l = i - 2048;
    src = w2; dst = w2t; R = 2048; C = 512; bx = l & 63; by = l >> 6;
  }
  int r0 = bx * 32, c0 = by * 32;
#pragma unroll
  for (int k = 0; k < 4; ++k)
    tile[ty + 8 * k][tx] = src[(size_t)(r0 + ty + 8 * k) * C + c0 + tx];
  __syncthreads();
#pragma unroll
  for (int k = 0; k < 4; ++k)
    dst[(size_t)(c0 + ty + 8 * k) * R + r0 + tx] = f2bf(tile[tx][ty + 8 * k]);
}

// ===== combined launch: QK gemm8p (blocks 0..255) + V proj (256..287) + =====
// ===== vsum (288..295). 512 threads. ========================================
__global__ __launch_bounds__(512, 1) void qkv_kernel(
    const u16* __restrict__ A, const u16* __restrict__ Wqk,
    const float* __restrict__ qkbias, u16* __restrict__ qk_f16,
    const u16* __restrict__ a64, const u16* __restrict__ Wvt,
    const float* __restrict__ bv, u16* __restrict__ v64t,
    const float* __restrict__ srow_part, const float* __restrict__ wv,
    float* __restrict__ vsum) {
  __shared__ u16 As[3][2][256 * 32];
  __shared__ u16 Bs[3][2][128 * 32];
  const int bid = blockIdx.x;
  const int tid = threadIdx.x;
  const int wid = tid >> 6, lane = tid & 63;
  const int la = lane & 15, lg = lane >> 4;

  if (bid >= 288) {
    // ---------------- vsum: b = bid-288, n = tid ----------------
    float* ssrow = (float*)As;  // 512 floats
    int b = bid - 288, n = tid;
    float acc = 0.f;
    for (int c = 0; c < 128; ++c) acc += srow_part[(size_t)c * 4096 + b * 512 + n];
    ssrow[n] = acc;
    __syncthreads();
    float a0 = 0.f, a1 = 0.f, a2 = 0.f, a3 = 0.f;
    for (int k = 0; k < 512; k += 4) {
      a0 = fmaf(ssrow[k + 0], wv[(size_t)(k + 0) * 512 + n], a0);
      a1 = fmaf(ssrow[k + 1], wv[(size_t)(k + 1) * 512 + n], a1);
      a2 = fmaf(ssrow[k + 2], wv[(size_t)(k + 2) * 512 + n], a2);
      a3 = fmaf(ssrow[k + 3], wv[(size_t)(k + 3) * 512 + n], a3);
    }
    vsum[b * 512 + n] = (a0 + a1) + (a2 + a3) + 1024.f * bv[n];
    return;
  }

  if (bid >= 256) {
    // ------------- V projection: 128x64 tile, 8 waves, dbuf ----------------
    u16* As2 = (u16*)As;          // [2][128*32]
    u16* Bs2 = As2 + 2 * 128 * 32;  // [2][64*32]
    int vb = bid - 256;
    const int row0 = (vb & 3) * 128, col0 = (vb >> 2) * 64;
    const int wm = wid >> 2, wn = wid & 3;
    f32x4 acc[4] = {};
    auto stage = [&](int buf, int k0) {
      {
        int p = tid, r = p >> 2, cg = (p & 3) ^ ((r >> 1) & 3);
        gload_lds16(a64 + (size_t)(row0 + r) * 512 + k0 + cg * 8,
                    ((char*)(As2 + buf * 128 * 32)) + p * 16);
      }
      if (tid < 256) {
        int p = tid, r = p >> 2, cg = (p & 3) ^ ((r >> 1) & 3);
        gload_lds16(Wvt + (size_t)(col0 + r) * 512 + k0 + cg * 8,
                    ((char*)(Bs2 + buf * 64 * 32)) + p * 16);
      }
    };
    stage(0, 0);
    __syncthreads();
    for (int t = 0; t < 16; ++t) {
      const int cur = t & 1;
      if (t + 1 < 16) stage(cur ^ 1, (t + 1) * 32);
      bf16x8 af[4], bfv;
#pragma unroll
      for (int m = 0; m < 4; ++m) {
        int r = wm * 64 + m * 16 + la;
        int cp = lg ^ ((r >> 1) & 3);
        af[m] = *(const bf16x8*)(((const char*)(As2 + cur * 128 * 32)) + r * 64 + cp * 16);
      }
      {
        int r = wn * 16 + la;
        int cp = lg ^ ((r >> 1) & 3);
        bfv = *(const bf16x8*)(((const char*)(Bs2 + cur * 64 * 32)) + r * 64 + cp * 16);
      }
#pragma unroll
      for (int m = 0; m < 4; ++m)
        acc[m] = __builtin_amdgcn_mfma_f32_16x16x32_bf16(af[m], bfv, acc[m], 0, 0, 0);
      __syncthreads();
    }
#pragma unroll
    for (int m = 0; m < 4; ++m) {
      int r = row0 + wm * 64 + m * 16 + lg * 4;
      int cc = col0 + wn * 16 + la;
      float bvv = bv[cc];
#pragma unroll
      for (int j = 0; j < 4; ++j) {
        float v = acc[m][j] + bvv;
        int rr = r + j;
        int bb = rr >> 6, tt = rr & 63, hh = cc >> 6, dd = cc & 63;
        v64t[(((size_t)bb * 8 + hh) * 64 + dd) * 64 + tt] = f2bf(v);
      }
    }
    return;
  }

  // ---------------- QK projection: gemm8p body, M=8192 N=1024 K=512 --------
  const int K = 512, N = 1024;
  const int wm = wid >> 2, wn = wid & 3;
  int lin = bid;  // 0..255
  int swz = (lin & 7) * 32 + (lin >> 3);
  int bx = swz >> 3, by = swz & 7;
  const int row0 = bx * 256, col0 = by * 128;
  const int nt = 8;
  f32x4 acc[8][2] = {};

  auto stageh = [&](int buf, int h, int k0) {
    int kh = k0 + h * 32;
    {
      int p = tid, r = p >> 2, cg = (p & 3) ^ ((r >> 1) & 3);
      gload_lds16(A + (size_t)(row0 + r) * K + kh + cg * 8,
                  ((char*)&As[buf][h][0]) + p * 16);
    }
    {
      int p = tid + 512, r = p >> 2, cg = (p & 3) ^ ((r >> 1) & 3);
      gload_lds16(A + (size_t)(row0 + r) * K + kh + cg * 8,
                  ((char*)&As[buf][h][0]) + p * 16);
    }
    {
      int p = tid, r = p >> 2, cg = (p & 3) ^ ((r >> 1) & 3);
      gload_lds16(Wqk + (size_t)(col0 + r) * K + kh + cg * 8,
                  ((char*)&Bs[buf][h][0]) + p * 16);
    }
  };

  stageh(0, 0, 0);
  stageh(0, 1, 0);
  stageh(1, 0, 64);
  stageh(1, 1, 64);
  asm volatile("s_waitcnt vmcnt(6)" ::: "memory");
  __builtin_amdgcn_s_barrier();
  __builtin_amdgcn_sched_barrier(0);

  for (int t = 0; t < nt; ++t) {
    const int buf = t % 3;
    const int nbuf = (t + 2) % 3;
    const bool pre = (t + 2 < nt);
#pragma unroll
    for (int h = 0; h < 2; ++h) {
      bf16x8 af[8], bf[2];
#pragma unroll
      for (int mf = 0; mf < 8; ++mf) {
        int r = wm * 128 + mf * 16 + la;
        int cp = lg ^ ((r >> 1) & 3);
        af[mf] = *(const bf16x8*)&As[buf][h][r * 32 + cp * 8];
      }
#pragma unroll
      for (int nf = 0; nf < 2; ++nf) {
        int r = wn * 32 + nf * 16 + la;
        int cp = lg ^ ((r >> 1) & 3);
        bf[nf] = *(const bf16x8*)&Bs[buf][h][r * 32 + cp * 8];
      }
      if (pre) stageh(nbuf, h, (t + 2) * 64);
      __builtin_amdgcn_sched_barrier(0);
      __builtin_amdgcn_s_barrier();
      __builtin_amdgcn_s_setprio(1);
#pragma unroll
      for (int mf = 0; mf < 8; ++mf)
#pragma unroll
        for (int nf = 0; nf < 2; ++nf)
          acc[mf][nf] = __builtin_amdgcn_mfma_f32_16x16x32_bf16(af[mf], bf[nf], acc[mf][nf], 0, 0, 0);
      __builtin_amdgcn_s_setprio(0);
      __builtin_amdgcn_sched_barrier(0);
      if (h == 0) __builtin_amdgcn_s_barrier();
    }
    if (pre)
      asm volatile("s_waitcnt vmcnt(6)" ::: "memory");
    else if (t + 1 < nt)
      asm volatile("s_waitcnt vmcnt(0)" ::: "memory");
    __builtin_amdgcn_s_barrier();
    __builtin_amdgcn_sched_barrier(0);
  }

#pragma unroll
  for (int mf = 0; mf < 8; ++mf) {
    int r = row0 + wm * 128 + mf * 16 + lg * 4;
#pragma unroll
    for (int nf = 0; nf < 2; ++nf) {
      int cc = col0 + wn * 32 + nf * 16 + la;
      float bvv = qkbias[cc];
#pragma unroll
      for (int j = 0; j < 4; ++j)
        qk_f16[(size_t)(r + j) * N + cc] = f2h(acc[mf][nf][j] + bvv);
    }
  }
}

// ============ 8-phase-family GEMM: 256x128 tile, BK=64, 8 waves =============
// OMODE: 1=bf16, 2=f16. KSPLIT: z>0 -> partial to Cv2 (bias only z==0).
template <int RELU, int OMODE, int KSPLIT>
__global__ __launch_bounds__(512, 1) void gemm8p_kernel(
    const u16* __restrict__ A, const u16* __restrict__ Bt,
    const float* __restrict__ bias, void* __restrict__ Cv, void* __restrict__ Cv2,
    int M, int N, int K) {
  __shared__ u16 As[3][2][256 * 32];
  __shared__ u16 Bs[3][2][128 * 32];
  const int tid = threadIdx.x;
  const int wid = tid >> 6, lane = tid & 63;
  const int wm = wid >> 2, wn = wid & 3;
  const int la = lane & 15, lg = lane >> 4;
  int nwg = gridDim.x * gridDim.y;
  int lin = blockIdx.y * gridDim.x + blockIdx.x;
  int swz = (lin & 7) * (nwg >> 3) + (lin >> 3);
  int bx = swz / gridDim.y, by = swz % gridDim.y;
  const int row0 = bx * 256, col0 = by * 128;
  const int z = (KSPLIT > 1) ? (int)blockIdx.z : 0;
  const int kbeg = z * (K / KSPLIT);
  const int nt = (K / KSPLIT) / 64;
  f32x4 acc[8][2] = {};

  auto stageh = [&](int buf, int h, int k0) {
    int kh = k0 + h * 32;
    {
      int p = tid, r = p >> 2, cg = (p & 3) ^ ((r >> 1) & 3);
      gload_lds16(A + (size_t)(row0 + r) * K + kh + cg * 8,
                  ((char*)&As[buf][h][0]) + p * 16);
    }
    {
      int p = tid + 512, r = p >> 2, cg = (p & 3) ^ ((r >> 1) & 3);
      gload_lds16(A + (size_t)(row0 + r) * K + kh + cg * 8,
                  ((char*)&As[buf][h][0]) + p * 16);
    }
    {
      int p = tid, r = p >> 2, cg = (p & 3) ^ ((r >> 1) & 3);
      gload_lds16(Bt + (size_t)(col0 + r) * K + kh + cg * 8,
                  ((char*)&Bs[buf][h][0]) + p * 16);
    }
  };

  stageh(0, 0, kbeg);
  stageh(0, 1, kbeg);
  stageh(1, 0, kbeg + 64);
  stageh(1, 1, kbeg + 64);
  asm volatile("s_waitcnt vmcnt(6)" ::: "memory");
  __builtin_amdgcn_s_barrier();
  __builtin_amdgcn_sched_barrier(0);

  for (int t = 0; t < nt; ++t) {
    const int buf = t % 3;
    const int nbuf = (t + 2) % 3;
    const bool pre = (t + 2 < nt);
#pragma unroll
    for (int h = 0; h < 2; ++h) {
      bf16x8 af[8], bf[2];
#pragma unroll
      for (int mf = 0; mf < 8; ++mf) {
        int r = wm * 128 + mf * 16 + la;
        int cp = lg ^ ((r >> 1) & 3);
        af[mf] = *(const bf16x8*)&As[buf][h][r * 32 + cp * 8];
      }
#pragma unroll
      for (int nf = 0; nf < 2; ++nf) {
        int r = wn * 32 + nf * 16 + la;
        int cp = lg ^ ((r >> 1) & 3);
        bf[nf] = *(const bf16x8*)&Bs[buf][h][r * 32 + cp * 8];
      }
      if (pre) stageh(nbuf, h, kbeg + (t + 2) * 64);
      __builtin_amdgcn_sched_barrier(0);
      __builtin_amdgcn_s_barrier();
      __builtin_amdgcn_s_setprio(1);
#pragma unroll
      for (int mf = 0; mf < 8; ++mf)
#pragma unroll
        for (int nf = 0; nf < 2; ++nf)
          acc[mf][nf] = __builtin_amdgcn_mfma_f32_16x16x32_bf16(af[mf], bf[nf], acc[mf][nf], 0, 0, 0);
      __builtin_amdgcn_s_setprio(0);
      __builtin_amdgcn_sched_barrier(0);
      if (h == 0) __builtin_amdgcn_s_barrier();
    }
    if (pre)
      asm volatile("s_waitcnt vmcnt(6)" ::: "memory");
    else if (t + 1 < nt)
      asm volatile("s_waitcnt vmcnt(0)" ::: "memory");
    __builtin_amdgcn_s_barrier();
    __builtin_amdgcn_sched_barrier(0);
  }

  void* Cout = (z == 0) ? Cv : Cv2;
#pragma unroll
  for (int mf = 0; mf < 8; ++mf) {
    int r = row0 + wm * 128 + mf * 16 + lg * 4;
#pragma unroll
    for (int nf = 0; nf < 2; ++nf) {
      int cc = col0 + wn * 32 + nf * 16 + la;
      float bvv = (z == 0) ? bias[cc] : 0.f;
#pragma unroll
      for (int j = 0; j < 4; ++j) {
        float v = acc[mf][nf][j] + bvv;
        if (RELU) v = fmaxf(v, 0.f);
        if constexpr (OMODE == 1)
          ((u16*)Cout)[(size_t)(r + j) * N + cc] = f2bf(v);
        else
          ((u16*)Cout)[(size_t)(r + j) * N + cc] = f2h(v);
      }
    }
  }
}

// ====== fine-phase 256x256 GEMM (m201-family), 4 phases per K-tile =========
template <int RELU, int KSPLIT>
__global__ __launch_bounds__(512, 1) void gemmfp_kernel(
    const u16* __restrict__ A, const u16* __restrict__ Bt,
    const float* __restrict__ bias, u16* __restrict__ C0, u16* __restrict__ C1,
    u16* __restrict__ C2, u16* __restrict__ C3, int M, int N, int K) {
  __shared__ u16 As[2][2][256 * 32];
  __shared__ u16 Bs[2][2][256 * 32];
  const int tid = threadIdx.x;
  const int wid = tid >> 6, lane = tid & 63;
  const int wm = wid >> 2, wn = wid & 3;
  const int la = lane & 15, lg = lane >> 4;
  int nwg = gridDim.x * gridDim.y;
  int lin = blockIdx.y * gridDim.x + blockIdx.x;
  int swz = (lin & 7) * (nwg >> 3) + (lin >> 3);
  int bx = swz / gridDim.y, by = swz % gridDim.y;
  const int row0 = bx * 256, col0 = by * 256;
  const int z = (KSPLIT > 1) ? (int)blockIdx.z : 0;
  const int kbeg = z * (K / KSPLIT);
  const int nt = (K / KSPLIT) / 64;
  f32x4 acc[8][4] = {};

  auto stageA = [&](int d, int s, int k0) {
#pragma unroll
    for (int j = 0; j < 2; ++j) {
      int p = tid + j * 512;
      int r = p >> 2, cg = (p & 3) ^ ((r >> 1) & 3);
      gload_lds16(A + (size_t)(row0 + r) * K + k0 + s * 32 + cg * 8,
                  ((char*)&As[d][s][0]) + p * 16);
    }
  };
  auto stageB = [&](int d, int s, int k0) {
#pragma unroll
    for (int j = 0; j < 2; ++j) {
      int p = tid + j * 512;
      int r = p >> 2, cg = (p & 3) ^ ((r >> 1) & 3);
      gload_lds16(Bt + (size_t)(col0 + r) * K + k0 + s * 32 + cg * 8,
                  ((char*)&Bs[d][s][0]) + p * 16);
    }
  };

  stageA(0, 0, kbeg);
  stageB(0, 0, kbeg);
  stageA(0, 1, kbeg);
  stageB(0, 1, kbeg);
  asm volatile("s_waitcnt vmcnt(0)" ::: "memory");
  __builtin_amdgcn_s_barrier();
  __builtin_amdgcn_sched_barrier(0);

  for (int t = 0; t < nt; ++t) {
    const int d = t & 1, nd = d ^ 1;
    const int k1 = kbeg + (t + 1) * 64;
    const bool pre = (t + 1 < nt);
    bf16x8 af[8], bf[2];
#pragma unroll
    for (int s = 0; s < 2; ++s) {
#pragma unroll
      for (int mf = 0; mf < 8; ++mf) {
        int r = wm * 128 + mf * 16 + la;
        int cp = lg ^ ((r >> 1) & 3);
        af[mf] = *(const bf16x8*)(((const char*)&As[d][s][0]) + r * 64 + cp * 16);
      }
#pragma unroll
      for (int nf = 0; nf < 2; ++nf) {
        int r = wn * 64 + nf * 16 + la;
        int cp = lg ^ ((r >> 1) & 3);
        bf[nf] = *(const bf16x8*)(((const char*)&Bs[d][s][0]) + r * 64 + cp * 16);
      }
      if (pre) stageA(nd, s, k1);
      __builtin_amdgcn_sched_barrier(0);
      __builtin_amdgcn_s_barrier();
      asm volatile("s_waitcnt lgkmcnt(0)" ::: "memory");
      __builtin_amdgcn_sched_barrier(0);
      __builtin_amdgcn_s_setprio(1);
#pragma unroll
      for (int mf = 0; mf < 8; ++mf)
#pragma unroll
        for (int nf = 0; nf < 2; ++nf)
          acc[mf][nf] = __builtin_amdgcn_mfma_f32_16x16x32_bf16(af[mf], bf[nf], acc[mf][nf], 0, 0, 0);
      __builtin_amdgcn_s_setprio(0);
      __builtin_amdgcn_sched_barrier(0);
      __builtin_amdgcn_s_barrier();
#pragma unroll
      for (int nf = 0; nf < 2; ++nf) {
        int r = wn * 64 + (nf + 2) * 16 + la;
        int cp = lg ^ ((r >> 1) & 3);
        bf[nf] = *(const bf16x8*)(((const char*)&Bs[d][s][0]) + r * 64 + cp * 16);
      }
      if (pre) stageB(nd, s, k1);
      __builtin_amdgcn_sched_barrier(0);
      if (pre)
        asm volatile("s_waitcnt vmcnt(4)" ::: "memory");
      else
        asm volatile("s_waitcnt vmcnt(0)" ::: "memory");
      __builtin_amdgcn_s_barrier();
      asm volatile("s_waitcnt lgkmcnt(0)" ::: "memory");
      __builtin_amdgcn_sched_barrier(0);
      __builtin_amdgcn_s_setprio(1);
#pragma unroll
      for (int mf = 0; mf < 8; ++mf)
#pragma unroll
        for (int nf = 0; nf < 2; ++nf)
          acc[mf][nf + 2] = __builtin_amdgcn_mfma_f32_16x16x32_bf16(af[mf], bf[nf], acc[mf][nf + 2], 0, 0, 0);
      __builtin_amdgcn_s_setprio(0);
      __builtin_amdgcn_sched_barrier(0);
      __builtin_amdgcn_s_barrier();
    }
  }

  u16* Cout = (z == 0) ? C0 : (z == 1) ? C1 : (z == 2) ? C2 : C3;
#pragma unroll
  for (int mf = 0; mf < 8; ++mf) {
    int r = row0 + wm * 128 + mf * 16 + lg * 4;
#pragma unroll
    for (int nf = 0; nf < 4; ++nf) {
      int cc = col0 + wn * 64 + nf * 16 + la;
      float bvv = (z == 0) ? bias[cc] : 0.f;
#pragma unroll
      for (int j = 0; j < 4; ++j) {
        float v = acc[mf][nf][j] + bvv;
        if (RELU) v = fmaxf(v, 0.f);
        Cout[(size_t)(r + j) * N + cc] = f2bf(v);
      }
    }
  }
}

// ---------- attention: 64-lag autocorr (f16 dot2) + MFMA PV, 16-row chunks --
__global__ __launch_bounds__(256) void attn_mfma_kernel(
    const u16* __restrict__ qk, const u16* __restrict__ v64t,
    const float* __restrict__ vsum, u16* __restrict__ attn_bf) {
  __shared__ u32 qE[16][64];
  __shared__ u32 qO[16][64];
  __shared__ u32 kp[16][32];
  __shared__ u16 coef[16][64];
  __shared__ u16 vtt[64][64];
  __shared__ float zc[16];
  __shared__ float Vs[64];
  int bid = blockIdx.x;
  int scnk = bid & 63, h = (bid >> 6) & 7, b = bid >> 9;
  int tid = threadIdx.x, wid = tid >> 6, lane = tid & 63;
  int bh = b * 8 + h;
  int row0 = b * 1024 + scnk * 16;

  {
    int p = tid, r = p >> 3, cc = p & 7;
    gload_lds16(v64t + ((size_t)bh * 4096 + r * 64 + ((cc ^ (r & 7)) * 8)),
                ((char*)vtt) + p * 16);
    p = tid + 256; r = p >> 3; cc = p & 7;
    gload_lds16(v64t + ((size_t)bh * 4096 + r * 64 + ((cc ^ (r & 7)) * 8)),
                ((char*)vtt) + p * 16);
  }
  for (int idx = tid; idx < 512; idx += 256) {
    int s = idx >> 5, j = (idx & 31) + 32;
    qE[s][j] = 0;
  }
  {
    if (tid < 128) {
      int s = tid >> 3, c = tid & 7;
      size_t grow = ((size_t)(row0 + s)) * 1024 + h * 64;
      *(f32x4*)&qE[s][c * 4] = *(const f32x4*)&qk[grow + c * 8];
    } else {
      int t2 = tid - 128;
      int s = t2 >> 3, c = t2 & 7;
      size_t grow = ((size_t)(row0 + s)) * 1024 + 512 + h * 64;
      *(f32x4*)&kp[s][c * 4] = *(const f32x4*)&qk[grow + c * 8];
    }
  }
  if (tid < 64) Vs[tid] = vsum[b * 512 + h * 64 + tid];
  __syncthreads();
  for (int idx = tid; idx < 512; idx += 256) {
    int s = idx >> 5, j = idx & 31;
    u32 a = qE[s][j], b2 = qE[s][j + 1];
    qO[s][j] = (a >> 16) | (b2 << 16);
    qO[s][j + 32] = 0;
  }
  __syncthreads();
  for (int i = 0; i < 4; ++i) {
    int s = wid * 4 + i;
    u32x4 kk4[8];
#pragma unroll
    for (int u = 0; u < 8; ++u) kk4[u] = *(const u32x4*)&kp[s][u * 4];
    int t = lane, sel = t & 1;
    const u32* qptr = (sel ? qO[s] : qE[s]) + (t >> 1);
    float c = 0.f;
#pragma unroll
    for (int u = 0; u < 8; ++u) {
#pragma unroll
      for (int v = 0; v < 4; ++v) c = dot2h(qptr[u * 4 + v], kk4[u][v], c);
    }
    float sc = c * 0.125f;  // 1/sqrt(64)
    float mx = fmaxf(sc, 0.f);
#pragma unroll
    for (int off = 32; off >= 1; off >>= 1) mx = fmaxf(mx, __shfl_xor(mx, off));
    float w = __expf(sc - mx), wz = __expf(-mx);
    float sw = w;
#pragma unroll
    for (int off = 32; off >= 1; off >>= 1) sw += __shfl_xor(sw, off);
    float inv = 1.f / (sw + 960.f * wz);
    *(u16*)(((char*)&coef[s][0]) + ((2 * t) ^ ((s & 7) << 4))) = f2bf((w - wz) * inv);
    if (lane == 0) zc[s] = wz * inv;
  }
  __syncthreads();
  {
    int la = lane & 15, lg = lane >> 4;
    int r = la;
    int n0 = wid * 16 + la;
    f32x4 a0 = {};
#pragma unroll
    for (int ks = 0; ks < 2; ++ks) {
      int lr = ks * 4 + lg;
      bf16x8 af = *(const bf16x8*)(((const char*)coef) + r * 128 + ((lr ^ (r & 7)) << 4));
      bf16x8 b0 = *(const bf16x8*)(((const char*)vtt) + n0 * 128 + ((lr ^ (n0 & 7)) << 4));
      a0 = __builtin_amdgcn_mfma_f32_16x16x32_bf16(af, b0, a0, 0, 0, 0);
    }
    int srl0 = lg * 4;
    float vs0 = Vs[wid * 16 + la];
#pragma unroll
    for (int j = 0; j < 4; ++j) {
      size_t rb = (size_t)(row0 + srl0 + j) * 512 + h * 64;
      attn_bf[rb + wid * 16 + la] = f2bf(a0[j] + zc[srl0 + j] * vs0);
    }
  }
}

// ---------------- reductions ------------------------------------------------
__device__ __forceinline__ void block_reduce_2(float& a, float& b, float* sbuf) {
  int tid = threadIdx.x, wid = tid >> 6, lane = tid & 63;
#pragma unroll
  for (int off = 32; off >= 1; off >>= 1) {
    a += __shfl_xor(a, off);
    b += __shfl_xor(b, off);
  }
  if (lane == 0) {
    sbuf[wid] = a;
    sbuf[4 + wid] = b;
  }
  __syncthreads();
  a = sbuf[0] + sbuf[1] + sbuf[2] + sbuf[3];
  b = sbuf[4] + sbuf[5] + sbuf[6] + sbuf[7];
  __syncthreads();
}

// out1 = LN(xa + xb + res; g, be); all bf16; writes bf16 IN-PLACE over res.
__global__ __launch_bounds__(256) void ln_res_kernel(
    const u16* __restrict__ xa, const u16* __restrict__ xb,
    u16* __restrict__ res_out,
    const float* __restrict__ g, const float* __restrict__ be) {
  __shared__ float sbuf[8];
  int row = blockIdx.x, tid = threadIdx.x;
  int d = tid * 2;
  size_t base = (size_t)row * 512 + d;
  u32 pa = *(const u32*)&xa[base];
  u32 pb = *(const u32*)&xb[base];
  u32 pr = *(const u32*)&res_out[base];
  float v0 = bf2f((u16)pa) + bf2f((u16)pb) + bf2f((u16)pr);
  float v1 = bf2f((u16)(pa >> 16)) + bf2f((u16)(pb >> 16)) + bf2f((u16)(pr >> 16));
  float s = v0 + v1, q = v0 * v0 + v1 * v1;
  block_reduce_2(s, q, sbuf);
  float mean = s * (1.f / 512.f);
  float var = q * (1.f / 512.f) - mean * mean;
  float rs = rsqrtf(var + 1e-6f);
  float2 gg = *(const float2*)&g[d];
  float2 bb = *(const float2*)&be[d];
  float o0 = (v0 - mean) * rs * gg.x + bb.x;
  float o1 = (v1 - mean) * rs * gg.y + bb.y;
  *(u32*)&res_out[base] = (u32)f2bf(o0) | ((u32)f2bf(o1) << 16);
}

// out = LN3( LN2(out1+fa+fb+fc+fd;g2,be2) + x ; g3,be3 ). all bf16 partials.
__global__ __launch_bounds__(256) void final_kernel(
    const u16* __restrict__ out1, const u16* __restrict__ fa,
    const u16* __restrict__ fb, const u16* __restrict__ fc,
    const u16* __restrict__ fd, const float* __restrict__ x,
    const float* __restrict__ g2, const float* __restrict__ be2,
    const float* __restrict__ g3, const float* __restrict__ be3,
    float* __restrict__ out) {
  __shared__ float sbuf[8];
  int row = blockIdx.x, tid = threadIdx.x;
  int d = tid * 2;
  size_t base = (size_t)row * 512 + d;
  u32 po = *(const u32*)&out1[base];
  u32 pa = *(const u32*)&fa[base];
  u32 pb = *(const u32*)&fb[base];
  u32 pc = *(const u32*)&fc[base];
  u32 pd = *(const u32*)&fd[base];
  float t0 = bf2f((u16)po) + bf2f((u16)pa) + bf2f((u16)pb) + bf2f((u16)pc) + bf2f((u16)pd);
  float t1 = bf2f((u16)(po >> 16)) + bf2f((u16)(pa >> 16)) + bf2f((u16)(pb >> 16)) +
             bf2f((u16)(pc >> 16)) + bf2f((u16)(pd >> 16));
  float s = t0 + t1, q = t0 * t0 + t1 * t1;
  block_reduce_2(s, q, sbuf);
  float mean = s * (1.f / 512.f);
  float var = q * (1.f / 512.f) - mean * mean;
  float rs = rsqrtf(var + 1e-6f);
  float2 g2v = *(const float2*)&g2[d];
  float2 b2v = *(const float2*)&be2[d];
  float2 xv = *(const float2*)&x[base];
  float y0 = (t0 - mean) * rs * g2v.x + b2v.x + xv.x;
  float y1 = (t1 - mean) * rs * g2v.y + b2v.y + xv.y;
  s = y0 + y1;
  q = y0 * y0 + y1 * y1;
  block_reduce_2(s, q, sbuf);
  mean = s * (1.f / 512.f);
  var = q * (1.f / 512.f) - mean * mean;
  rs = rsqrtf(var + 1e-6f);
  float2 g3v = *(const float2*)&g3[d];
  float2 b3v = *(const float2*)&be3[d];
  float2 o = make_float2((y0 - mean) * rs * g3v.x + b3v.x,
                         (y1 - mean) * rs * g3v.y + b3v.y);
  *(float2*)&out[base] = o;
}

// ---------------------------------------------------------------------------
extern "C" void kernel_launch(void* const* d_in, const int* in_sizes, int n_in,
                              void* d_out, int out_size, void* d_ws, size_t ws_size,
                              hipStream_t stream) {
  const float* x = (const float*)d_in[0];
  const float* wq = (const float*)d_in[1];
  const float* bq = (const float*)d_in[2];
  const float* wk = (const float*)d_in[3];
  const float* bk = (const float*)d_in[4];
  const float* wv = (const float*)d_in[5];
  const float* bv = (const float*)d_in[6];
  const float* wo = (const float*)d_in[7];
  const float* bo = (const float*)d_in[8];
  const float* w1 = (const float*)d_in[9];
  const float* b1 = (const float*)d_in[10];
  const float* w2 = (const float*)d_in[11];
  const float* b2 = (const float*)d_in[12];
  const float* g1 = (const float*)d_in[13];
  const float* be1 = (const float*)d_in[14];
  const float* g2 = (const float*)d_in[15];
  const float* be2 = (const float*)d_in[16];
  const float* g3 = (const float*)d_in[17];
  const float* be3 = (const float*)d_in[18];
  float* out = (float*)d_out;

  const size_t MS = 8192ull * 512ull;
  float* srow_part = (float*)d_ws;      // 128*8*512 = 524288 floats (2 MB)
  float* vsumb = srow_part + 524288;    // 8*512
  float* qkbias = vsumb + 4096;         // 1024
  u16* qk_f16 = (u16*)(qkbias + 1024);  // 8192*1024 f16; later FFN2 partials 0,1
  u16* hidden = qk_f16 + 8192ull * 1024;   // 8192*2048 bf16
  u16* seas_bf = hidden + 8192ull * 2048;  // MS bf16; ln_res overwrites -> out1
  u16* attn_bf = seas_bf + MS;             // MS bf16
  u16* wo0 = attn_bf + MS;                 // WO partial z=0; later FFN2 partial 2
  u16* wo1 = wo0 + MS;                     // WO partial z=1; later FFN2 partial 3
  u16* v64t = wo1 + MS;                    // 64*64*64
  u16* a64_bf = v64t + 512 * 512;          // 512*512
  u16* wqkt = a64_bf + 512 * 512;          // [1024,512]
  u16* wvt = wqkt + 1024 * 512;
  u16* wot = wvt + 512 * 512;
  u16* w1t = wot + 512 * 512;       // [2048,512]
  u16* w2t = w1t + 2048ull * 512;   // [512,2048]
  u16* ff0 = qk_f16;                // FFN2 partials (qk dead after attn,
  u16* ff1 = ff0 + MS;              //  wo0/wo1 dead after ln_res)
  u16* ff2 = wo0;
  u16* ff3 = wo1;

  prep_kernel<<<4100, 256, 0, stream>>>(
      wq, wk, wv, wo, w1, w2, bq, bk, wqkt, wvt, wot, w1t, w2t, qkbias,
      x, seas_bf, a64_bf, srow_part);

  // combined: QK projection (f16) + V projection (transposed bf16) + vsum
  qkv_kernel<<<296, 512, 0, stream>>>(
      seas_bf, wqkt, qkbias, qk_f16, a64_bf, wvt, bv, v64t,
      srow_part, wv, vsumb);

  attn_mfma_kernel<<<4096, 256, 0, stream>>>(qk_f16, v64t, vsumb, attn_bf);

  // WO projection, split-K=2, bf16 partials
  gemm8p_kernel<0, 1, 2><<<dim3(32, 4, 2), 512, 0, stream>>>(
      attn_bf, wot, bo, wo0, wo1, 8192, 512, 512);
  // out1 = LN(wo0+wo1+seasonal) written in-place over seas_bf
  ln_res_kernel<<<8192, 256, 0, stream>>>(wo0, wo1, seas_bf, g1, be1);

  // FFN1: fine-phase 256x256, grid (32,8) = exact fill
  gemmfp_kernel<1, 1><<<dim3(32, 8), 512, 0, stream>>>(
      seas_bf, w1t, b1, hidden, nullptr, nullptr, nullptr, 8192, 2048, 512);
  // FFN2: fine-phase 256x256, split-K=4 -> (32,2,4) = 256 blocks
  gemmfp_kernel<0, 4><<<dim3(32, 2, 4), 512, 0, stream>>>(
      hidden, w2t, b2, ff0, ff1, ff2, ff3, 8192, 512, 2048);

  final_kernel<<<8192, 256, 0, stream>>>(seas_bf, ff0, ff1, ff2, ff3, x,
                                         g2, be2, g3, be3, out);
}